// Round 21
// baseline (54068.988 us; speedup 1.0000x reference)
//
#include <hip/hip_runtime.h>
#include <hip/hip_bf16.h>

typedef __attribute__((ext_vector_type(4))) float f32x4;

// ---------- all-f32 GEMM: C(M,N) = A(M,K) @ W(N,K)^T + bias ----------
// 64x64 tile, 4x4 per thread. MODE 0: out; 1: relu; 2: residual += (ld 1024, opt remap); 3: sigmoid
template<int MODE>
__global__ __launch_bounds__(256)
void gemm_f32(const float* __restrict__ A, const float* __restrict__ W,
              const float* __restrict__ bias, float* __restrict__ Cout,
              int N, int K, int remap)
{
  __shared__ float As[64][17];
  __shared__ float Ws[64][17];
  const int tid = threadIdx.x;
  const int tx = tid & 15, ty = tid >> 4;
  float acc[4][4];
  #pragma unroll
  for (int i=0;i<4;++i)
    #pragma unroll
    for (int j=0;j<4;++j) acc[i][j] = 0.f;

  for (int kt = 0; kt < K; kt += 16){
    #pragma unroll
    for (int e=0;e<4;++e){
      const int idx = tid + e*256;
      const int r = idx >> 4, c = idx & 15;
      As[r][c] = A[(size_t)(blockIdx.y*64 + r)*K + kt + c];
      Ws[r][c] = W[(size_t)(blockIdx.x*64 + r)*K + kt + c];
    }
    __syncthreads();
    #pragma unroll
    for (int k=0;k<16;++k){
      float ar[4], wr[4];
      #pragma unroll
      for (int i=0;i<4;++i) ar[i] = As[ty*4+i][k];
      #pragma unroll
      for (int j=0;j<4;++j) wr[j] = Ws[tx*4+j][k];
      #pragma unroll
      for (int i=0;i<4;++i)
        #pragma unroll
        for (int j=0;j<4;++j) acc[i][j] += ar[i]*wr[j];
    }
    __syncthreads();
  }

  #pragma unroll
  for (int i=0;i<4;++i){
    const int row = blockIdx.y*64 + ty*4 + i;
    #pragma unroll
    for (int j=0;j<4;++j){
      const int col = blockIdx.x*64 + tx*4 + j;
      float v = acc[i][j] + bias[col];
      if (MODE==0)      Cout[(size_t)row*N + col] = v;
      else if (MODE==1) Cout[(size_t)row*N + col] = fmaxf(v, 0.f);
      else if (MODE==2){
        const int orow = remap ? ((row>>7)*144 + 16 + (row&127)) : row;
        Cout[(size_t)orow*1024 + col] += v;
      }
      else if (MODE==3) Cout[(size_t)row*N + col] = 1.f/(1.f+expf(-v));
    }
  }
}

// ---------- all-f32 brute attention: one thread per (b,h,q-row) ----------
__global__ __launch_bounds__(256)
void attn_ref(const float* __restrict__ Qp, int ldq,
              const float* __restrict__ Kp, const float* __restrict__ Vp, int ldkv,
              float* __restrict__ Op, int nq, int qoff)
{
  const int b = blockIdx.x >> 4, h = blockIdx.x & 15;
  const int t = threadIdx.x;
  if (t >= nq) return;
  const float* Qr = Qp + (size_t)(b*nq + t)*ldq  + h*64;
  const float* Kb = Kp + (size_t)(b*144)*ldkv + h*64;
  const float* Vb = Vp + (size_t)(b*144)*ldkv + h*64;
  float q[64], o[64];
  #pragma unroll
  for (int d=0; d<64; ++d){ q[d] = Qr[d]; o[d] = 0.f; }
  float m = -1e30f, l = 0.f;
  const int qi = t + qoff;
  for (int j=0; j<144; ++j){
    const float* Kr = Kb + (size_t)j*ldkv;
    float s = 0.f;
    #pragma unroll
    for (int d=0; d<64; ++d) s += q[d]*Kr[d];
    s *= 0.125f;
    if (qi >= 0 && j >= 16 && (j-16) > qi) s = -1e30f;
    const float mn = fmaxf(m, s);
    const float corr = expf(m - mn);
    const float p = expf(s - mn);
    l = l*corr + p;
    const float* Vr = Vb + (size_t)j*ldkv;
    #pragma unroll
    for (int d=0; d<64; ++d) o[d] = o[d]*corr + p*Vr[d];
    m = mn;
  }
  const float inv = 1.f/l;
  float* Or = Op + (size_t)(b*nq + t)*1024 + h*64;
  #pragma unroll
  for (int d=0; d<64; ++d) Or[d] = o[d]*inv;
}

// ---------- LN helpers ----------
__device__ __forceinline__ void ln_stats(float s, float s2, float* red, int tid,
                                         float& mu, float& rstd)
{
  #pragma unroll
  for (int d=1; d<64; d<<=1){ s += __shfl_xor(s,d); s2 += __shfl_xor(s2,d); }
  if ((tid&63)==0){ red[tid>>6] = s; red[4+(tid>>6)] = s2; }
  __syncthreads();
  s  = red[0]+red[1]+red[2]+red[3];
  s2 = red[4]+red[5]+red[6]+red[7];
  mu = s * (1.f/1024.f);
  float var = s2*(1.f/1024.f) - mu*mu;
  rstd = rsqrtf(fmaxf(var,0.f) + 1e-5f);
}

__global__ __launch_bounds__(256)
void buildz_ln(const float* __restrict__ mem, const int* __restrict__ ids,
               const float* __restrict__ emb, const float* __restrict__ pos,
               const float* __restrict__ gam, const float* __restrict__ bet,
               float* __restrict__ z, float* __restrict__ out, int k)
{
  __shared__ float red[8];
  const int row = blockIdx.x;
  const int b = row / 144, t = row % 144;
  const int tid = threadIdx.x, c0 = tid*4;
  float v[4];
  if (t < 16){
    const f32x4 mv = *(const f32x4*)(mem + (size_t)(b*16+t)*1024 + c0);
    v[0]=mv[0]; v[1]=mv[1]; v[2]=mv[2]; v[3]=mv[3];
  } else {
    const int tok = ids[b*2048 + k*128 + (t-16)];
    const f32x4 e4 = *(const f32x4*)(emb + (size_t)tok*1024 + c0);
    v[0]=e4[0]; v[1]=e4[1]; v[2]=e4[2]; v[3]=e4[3];
  }
  const f32x4 p4 = *(const f32x4*)(pos + (size_t)t*1024 + c0);
  v[0]+=p4[0]; v[1]+=p4[1]; v[2]+=p4[2]; v[3]+=p4[3];
  f32x4 zz; zz[0]=v[0]; zz[1]=v[1]; zz[2]=v[2]; zz[3]=v[3];
  *(f32x4*)(z + (size_t)row*1024 + c0) = zz;
  float s = v[0]+v[1]+v[2]+v[3];
  float s2 = v[0]*v[0]+v[1]*v[1]+v[2]*v[2]+v[3]*v[3];
  float mu, rstd; ln_stats(s, s2, red, tid, mu, rstd);
  const f32x4 g4 = *(const f32x4*)(gam + c0);
  const f32x4 b4 = *(const f32x4*)(bet + c0);
  f32x4 o4;
  o4[0] = (v[0]-mu)*rstd*g4[0]+b4[0];
  o4[1] = (v[1]-mu)*rstd*g4[1]+b4[1];
  o4[2] = (v[2]-mu)*rstd*g4[2]+b4[2];
  o4[3] = (v[3]-mu)*rstd*g4[3]+b4[3];
  *(f32x4*)(out + (size_t)row*1024 + c0) = o4;
}

__global__ __launch_bounds__(256)
void ln_f32(const float* __restrict__ src, const float* __restrict__ gam,
            const float* __restrict__ bet, float* __restrict__ out, int remap)
{
  __shared__ float red[8];
  const int row = blockIdx.x;
  const int srow = remap ? ((row>>7)*144 + 16 + (row&127)) : row;
  const int tid = threadIdx.x, c0 = tid*4;
  const f32x4 xv = *(const f32x4*)(src + (size_t)srow*1024 + c0);
  float v[4] = {xv[0], xv[1], xv[2], xv[3]};
  float s = v[0]+v[1]+v[2]+v[3];
  float s2 = v[0]*v[0]+v[1]*v[1]+v[2]*v[2]+v[3]*v[3];
  float mu, rstd; ln_stats(s, s2, red, tid, mu, rstd);
  const f32x4 g4 = *(const f32x4*)(gam + c0);
  const f32x4 b4 = *(const f32x4*)(bet + c0);
  f32x4 o4;
  o4[0] = (v[0]-mu)*rstd*g4[0]+b4[0];
  o4[1] = (v[1]-mu)*rstd*g4[1]+b4[1];
  o4[2] = (v[2]-mu)*rstd*g4[2]+b4[2];
  o4[3] = (v[3]-mu)*rstd*g4[3]+b4[3];
  *(f32x4*)(out + (size_t)row*1024 + c0) = o4;
}

__global__ __launch_bounds__(256)
void ln_kv(const float* __restrict__ pmem, const float* __restrict__ enc,
           const float* __restrict__ gam, const float* __restrict__ bet,
           float* __restrict__ out, int k)
{
  __shared__ float red[8];
  const int row = blockIdx.x;
  const int b = row / 144, t = row % 144;
  const int tid = threadIdx.x, c0 = tid*4;
  const float* src = (t < 16) ? (pmem + (size_t)(b*16+t)*1024)
                              : (enc + ((size_t)b*2048 + k*128 + (t-16))*1024);
  const f32x4 x4 = *(const f32x4*)(src + c0);
  float v[4] = {x4[0], x4[1], x4[2], x4[3]};
  float s = v[0]+v[1]+v[2]+v[3];
  float s2 = v[0]*v[0]+v[1]*v[1]+v[2]*v[2]+v[3]*v[3];
  float mu, rstd; ln_stats(s, s2, red, tid, mu, rstd);
  const f32x4 g4 = *(const f32x4*)(gam + c0);
  const f32x4 b4 = *(const f32x4*)(bet + c0);
  f32x4 o4;
  o4[0] = (v[0]-mu)*rstd*g4[0]+b4[0];
  o4[1] = (v[1]-mu)*rstd*g4[1]+b4[1];
  o4[2] = (v[2]-mu)*rstd*g4[2]+b4[2];
  o4[3] = (v[3]-mu)*rstd*g4[3]+b4[3];
  *(f32x4*)(out + (size_t)row*1024 + c0) = o4;
}

// mem_cand (z rows t<16) -> compact f32 (256 x 1024)
__global__ __launch_bounds__(256)
void mc_cast(const float* __restrict__ z, float* __restrict__ mcb)
{
  const int i = blockIdx.x*1024 + threadIdx.x*4;
  const int r = i >> 10, c = i & 1023;
  const int b = r >> 4, t = r & 15;
  const f32x4 zv = *(const f32x4*)(z + (size_t)(b*144+t)*1024 + c);
  *(f32x4*)(mcb + i) = zv;
}

// mem = (k==0) ? mem_cand : g*mem_cand + (1-g)*mem
__global__ __launch_bounds__(256)
void gate_apply(const float* __restrict__ z, const float* __restrict__ gate,
                float* __restrict__ mem, int k)
{
  const int i = blockIdx.x*1024 + threadIdx.x*4;
  const int r = i >> 10, c = i & 1023;
  const int b = r >> 4, t = r & 15;
  const f32x4 mc = *(const f32x4*)(z + (size_t)(b*144+t)*1024 + c);
  f32x4 out;
  if (k == 0){
    out = mc;
  } else {
    const f32x4 gg = *(const f32x4*)(gate + i);
    const f32x4 mo = *(const f32x4*)(mem + i);
    out[0] = gg[0]*mc[0] + (1.f-gg[0])*mo[0];
    out[1] = gg[1]*mc[1] + (1.f-gg[1])*mo[1];
    out[2] = gg[2]*mc[2] + (1.f-gg[2])*mo[2];
    out[3] = gg[3]*mc[3] + (1.f-gg[3])*mo[3];
  }
  *(f32x4*)(mem + i) = out;
}

// out[b, k*128+i, :] = z[b*144+16+i, :]   *** F32 STORE (the fix) ***
__global__ __launch_bounds__(256)
void writeout(const float* __restrict__ z, float* __restrict__ out, int k)
{
  const int row = blockIdx.x;          // 0..2047
  const int b = row >> 7, t = row & 127;
  const int c0 = threadIdx.x*4;
  const f32x4 zv = *(const f32x4*)(z + (size_t)(b*144+16+t)*1024 + c0);
  *(f32x4*)(out + ((size_t)b*2048 + k*128 + t)*1024 + c0) = zv;
}

extern "C" void kernel_launch(void* const* d_in, const int* in_sizes, int n_in,
                              void* d_out, int out_size, void* d_ws, size_t ws_size,
                              hipStream_t stream)
{
  const int*   in_res   = (const int*)d_in[0];
  const float* enc_out  = (const float*)d_in[1];
  const float* enc_mem  = (const float*)d_in[2];
  const float* emb      = (const float*)d_in[3];
  const float* Wmem     = (const float*)d_in[4];
  const float* bmem     = (const float*)d_in[5];
  const float* pos      = (const float*)d_in[6];
  const float* Wqkv_s   = (const float*)d_in[7];
  const float* bqkv_s   = (const float*)d_in[8];
  const float* Wo_s     = (const float*)d_in[9];
  const float* bo_s     = (const float*)d_in[10];
  const float* g_la     = (const float*)d_in[11];
  const float* b_la     = (const float*)d_in[12];
  const float* W1       = (const float*)d_in[13];
  const float* b1       = (const float*)d_in[14];
  const float* W2       = (const float*)d_in[15];
  const float* b2       = (const float*)d_in[16];
  const float* g_lf     = (const float*)d_in[17];
  const float* b_lf     = (const float*)d_in[18];
  const float* Wencm    = (const float*)d_in[19];
  const float* bencm    = (const float*)d_in[20];
  const float* Wqkv_c   = (const float*)d_in[21];
  const float* bqkv_c   = (const float*)d_in[22];
  const float* Wo_c     = (const float*)d_in[23];
  const float* bo_c     = (const float*)d_in[24];
  const float* g_lq     = (const float*)d_in[25];
  const float* b_lq     = (const float*)d_in[26];
  const float* g_lkv    = (const float*)d_in[27];
  const float* b_lkv    = (const float*)d_in[28];
  const float* W1c      = (const float*)d_in[29];
  const float* b1c      = (const float*)d_in[30];
  const float* W2c      = (const float*)d_in[31];
  const float* b2c      = (const float*)d_in[32];
  const float* g_lfc    = (const float*)d_in[33];
  const float* b_lfc    = (const float*)d_in[34];
  const float* Wg       = (const float*)d_in[35];
  const float* bg       = (const float*)d_in[36];

  char* ws = (char*)d_ws;
  size_t off = 0;
  auto alloc = [&](size_t bytes)->void*{
    void* p = ws + off; off += (bytes + 255) & ~(size_t)255; return p;
  };
  float* z     = (float*)alloc((size_t)2304*1024*4);
  float* lnbuf = (float*)alloc((size_t)2304*1024*4);
  float* qkv   = (float*)alloc((size_t)2304*3072*4);
  float* attnb = (float*)alloc((size_t)2304*1024*4);
  float* mid   = (float*)alloc((size_t)2304*4096*4);
  float* kvb   = (float*)alloc((size_t)2304*1024*4);
  float* memf  = (float*)alloc((size_t)256*1024*4);
  float* pmem  = (float*)alloc((size_t)256*1024*4);
  float* mcb   = (float*)alloc((size_t)256*1024*4);
  float* gate  = (float*)alloc((size_t)256*1024*4);

  float* qc  = qkv;
  float* kvc = qkv + (size_t)2048*1024;
  float* outf = (float*)d_out;

  dim3 blk(256);
  // prologue: mem0 and proj_mem
  gemm_f32<0><<<dim3(16,4), blk, 0, stream>>>(enc_mem, Wmem,  bmem,  memf, 1024, 1024, 0);
  gemm_f32<0><<<dim3(16,4), blk, 0, stream>>>(enc_mem, Wencm, bencm, pmem, 1024, 1024, 0);

  for (int k = 0; k < 16; ++k){
    buildz_ln<<<2304, blk, 0, stream>>>(memf, in_res, emb, pos, g_la, b_la, z, lnbuf, k);
    gemm_f32<0><<<dim3(48,36), blk, 0, stream>>>(lnbuf, Wqkv_s, bqkv_s, qkv, 3072, 1024, 0);
    attn_ref<<<256, blk, 0, stream>>>(qkv, 3072, qkv+1024, qkv+2048, 3072, attnb, 144, -16);
    gemm_f32<2><<<dim3(16,36), blk, 0, stream>>>(attnb, Wo_s, bo_s, z, 1024, 1024, 0);
    ln_f32<<<2304, blk, 0, stream>>>(z, g_lf, b_lf, lnbuf, 0);
    gemm_f32<1><<<dim3(64,36), blk, 0, stream>>>(lnbuf, W1, b1, mid, 4096, 1024, 0);
    gemm_f32<2><<<dim3(16,36), blk, 0, stream>>>(mid, W2, b2, z, 1024, 4096, 0);
    // cross block
    ln_f32<<<2048, blk, 0, stream>>>(z, g_lq, b_lq, lnbuf, 1);
    gemm_f32<0><<<dim3(16,32), blk, 0, stream>>>(lnbuf, Wqkv_c, bqkv_c, qc, 1024, 1024, 0);
    ln_kv<<<2304, blk, 0, stream>>>(pmem, enc_out, g_lkv, b_lkv, kvb, k);
    gemm_f32<0><<<dim3(32,36), blk, 0, stream>>>(kvb, Wqkv_c + (size_t)1024*1024,
                                                 bqkv_c + 1024, kvc, 2048, 1024, 0);
    attn_ref<<<256, blk, 0, stream>>>(qc, 1024, kvc, kvc+1024, 2048, attnb, 128, 0);
    gemm_f32<2><<<dim3(16,32), blk, 0, stream>>>(attnb, Wo_c, bo_c, z, 1024, 1024, 1);
    ln_f32<<<2048, blk, 0, stream>>>(z, g_lfc, b_lfc, lnbuf, 1);
    gemm_f32<1><<<dim3(64,32), blk, 0, stream>>>(lnbuf, W1c, b1c, mid, 4096, 1024, 0);
    gemm_f32<2><<<dim3(16,32), blk, 0, stream>>>(mid, W2c, b2c, z, 1024, 4096, 1);
    writeout<<<2048, blk, 0, stream>>>(z, outf, k);
    // memory gate
    mc_cast<<<256, blk, 0, stream>>>(z, mcb);
    gemm_f32<3><<<dim3(16,4), blk, 0, stream>>>(mcb, Wg, bg, gate, 1024, 1024, 0);
    gate_apply<<<256, blk, 0, stream>>>(z, gate, memf, k);
  }
}

// Round 22
// 7273.683 us; speedup vs baseline: 7.4335x; 7.4335x over previous
//
#include <hip/hip_runtime.h>
#include <hip/hip_bf16.h>

#define AS1 __attribute__((address_space(1)))
#define AS3 __attribute__((address_space(3)))

typedef unsigned short u16;
typedef __attribute__((ext_vector_type(8))) short short8;
typedef __attribute__((ext_vector_type(4))) float f32x4;

__device__ __forceinline__ float b2f(u16 u){ return __uint_as_float(((unsigned)u)<<16); }
__device__ __forceinline__ u16 f2b(float f){
  unsigned x = __float_as_uint(f);
  return (u16)((x + 0x7FFFu + ((x>>16)&1u)) >> 16);
}

// ---------- f32 -> bf16 cast (prologue weight conversion) ----------
__global__ __launch_bounds__(256)
void castk(const float* __restrict__ src, u16* __restrict__ dst, int n)
{
  const int i = (blockIdx.x*256 + threadIdx.x)*4;
  if (i < n){
    const f32x4 v = *(const f32x4*)(src + i);
    ushort4 o; o.x=f2b(v[0]); o.y=f2b(v[1]); o.z=f2b(v[2]); o.w=f2b(v[3]);
    *(ushort4*)(dst + i) = o;
  }
}

// ---------- MFMA GEMM: C(M,N) = A(M,K) @ W(N,K)^T + bias ----------
// MODE 0: bf16 out; 1: bf16 relu; 2: f32 residual += (ld 1024, opt h-row remap);
// MODE 3: f32 sigmoid; 4: f32 out
template<int MODE>
__global__ __launch_bounds__(256)
void gemm_bt(const u16* __restrict__ A, const u16* __restrict__ W,
             const float* __restrict__ bias, void* __restrict__ Cout,
             int N, int K, int remap)
{
  __shared__ u16 Al[128*64];
  __shared__ u16 Bl[128*64];
  const int tid  = threadIdx.x;
  const int lane = tid & 63;
  const int w    = tid >> 6;
  const int wr = (w>>1)*64, wc = (w&1)*64;
  const int fr = lane & 15;
  const int fk = (lane>>4)*8;
  const int r8 = tid >> 3;
  const int c8 = (tid & 7)*8;
  const u16* ag = A + (size_t)(blockIdx.y*128 + r8)*K + c8;
  const u16* bg = W + (size_t)(blockIdx.x*128 + r8)*K + c8;
  u16* al = &Al[r8*64 + c8];
  u16* bl = &Bl[r8*64 + c8];

  f32x4 acc[4][4];
  #pragma unroll
  for (int m=0;m<4;++m)
    #pragma unroll
    for (int n=0;n<4;++n) acc[m][n] = (f32x4){0.f,0.f,0.f,0.f};

  for (int kt=0; kt<K; kt+=64){
    #pragma unroll
    for (int r=0;r<4;++r){
      __builtin_amdgcn_global_load_lds((const AS1 void*)(ag + (size_t)(r*32)*K + kt),
                                       (AS3 void*)(al + r*32*64), 16, 0, 0);
      __builtin_amdgcn_global_load_lds((const AS1 void*)(bg + (size_t)(r*32)*K + kt),
                                       (AS3 void*)(bl + r*32*64), 16, 0, 0);
    }
    __syncthreads();
    #pragma unroll
    for (int kk=0; kk<64; kk+=32){
      short8 a[4], b[4];
      #pragma unroll
      for (int m=0;m<4;++m) a[m] = *(const short8*)&Al[(wr+m*16+fr)*64 + kk + fk];
      #pragma unroll
      for (int n=0;n<4;++n) b[n] = *(const short8*)&Bl[(wc+n*16+fr)*64 + kk + fk];
      #pragma unroll
      for (int m=0;m<4;++m)
        #pragma unroll
        for (int n=0;n<4;++n)
          acc[m][n] = __builtin_amdgcn_mfma_f32_16x16x32_bf16(a[m], b[n], acc[m][n], 0, 0, 0);
    }
    __syncthreads();
  }

  const int rsub = (lane>>4)*4;
  #pragma unroll
  for (int n=0;n<4;++n){
    const int col = blockIdx.x*128 + wc + n*16 + fr;
    const float bv = bias[col];
    #pragma unroll
    for (int m=0;m<4;++m){
      const int row0 = blockIdx.y*128 + wr + m*16 + rsub;
      #pragma unroll
      for (int r=0;r<4;++r){
        const int row = row0 + r;
        float v = acc[m][n][r] + bv;
        if (MODE==0) ((u16*)Cout)[(size_t)row*N + col] = f2b(v);
        else if (MODE==1) ((u16*)Cout)[(size_t)row*N + col] = f2b(fmaxf(v,0.f));
        else if (MODE==2){
          const int orow = remap ? ((row>>7)*144 + 16 + (row&127)) : row;
          float* p = (float*)Cout + (size_t)orow*1024 + col;
          *p += v;
        }
        else if (MODE==3) ((float*)Cout)[(size_t)row*N + col] = 1.f/(1.f+expf(-v));
        else ((float*)Cout)[(size_t)row*N + col] = v;
      }
    }
  }
}

// ---------- MFMA attention: per-(b,h) block, kv len fixed 144 ----------
// mask: masked iff qi>=0 && j>=16 && j-16>qi, qi = token + qoff (-16 self, 0 cross)
__global__ __launch_bounds__(256)
void attn_kernel(const u16* __restrict__ Qp, int ldq,
                 const u16* __restrict__ Kp, const u16* __restrict__ Vp, int ldkv,
                 u16* __restrict__ Op, int nq, int qoff)
{
  __shared__ u16 Kl[144*64];
  __shared__ u16 Vt[64*160];
  __shared__ u16 Pl[4][16*160];
  const int tid = threadIdx.x, lane = tid & 63, w = tid >> 6;
  const int b = blockIdx.x >> 4, h = blockIdx.x & 15;
  const u16* Qb = Qp + (size_t)(b*nq)*ldq  + h*64;
  const u16* Kb = Kp + (size_t)(b*144)*ldkv + h*64;
  const u16* Vb = Vp + (size_t)(b*144)*ldkv + h*64;
  u16* Ob = Op + (size_t)(b*nq)*1024 + h*64;

  for (int i = tid*4; i < 64*160; i += 1024){ ushort4 zz = {0,0,0,0}; *(ushort4*)&Vt[i] = zz; }
  for (int i = tid*4; i < 4*16*160; i += 1024){ ushort4 zz = {0,0,0,0}; *(ushort4*)&Pl[0][i] = zz; }
  __syncthreads();

  for (int idx = tid*4; idx < 144*64; idx += 1024){
    const int j = idx >> 6, c = idx & 63;
    ushort4 kk4 = *(const ushort4*)(Kb + (size_t)j*ldkv + c);
    *(ushort4*)&Kl[j*64 + c] = kk4;
    ushort4 vv4 = *(const ushort4*)(Vb + (size_t)j*ldkv + c);
    Vt[(c+0)*160 + j] = vv4.x; Vt[(c+1)*160 + j] = vv4.y;
    Vt[(c+2)*160 + j] = vv4.z; Vt[(c+3)*160 + j] = vv4.w;
  }
  __syncthreads();

  const int fr = lane & 15;
  const int fkb = (lane>>4)*8;
  const int rsub = (lane>>4)*4;
  const int ntiles = nq >> 4;
  for (int qt = w; qt < ntiles; qt += 4){
    const int t0 = qt*16;
    short8 qa0 = *(const short8*)(Qb + (size_t)(t0+fr)*ldq + fkb);
    short8 qa1 = *(const short8*)(Qb + (size_t)(t0+fr)*ldq + 32 + fkb);
    f32x4 s[9];
    #pragma unroll
    for (int ct=0; ct<9; ++ct){
      f32x4 z = (f32x4){0.f,0.f,0.f,0.f};
      short8 b0 = *(const short8*)&Kl[(ct*16+fr)*64 + fkb];
      z = __builtin_amdgcn_mfma_f32_16x16x32_bf16(qa0, b0, z, 0,0,0);
      short8 b1 = *(const short8*)&Kl[(ct*16+fr)*64 + 32 + fkb];
      z = __builtin_amdgcn_mfma_f32_16x16x32_bf16(qa1, b1, z, 0,0,0);
      s[ct] = z;
    }
    #pragma unroll
    for (int r=0;r<4;++r){
      const int t = t0 + rsub + r;
      const int qi = t + qoff;
      float vals[9];
      float mx = -1e30f;
      #pragma unroll
      for (int ct=0; ct<9; ++ct){
        const int j = ct*16 + fr;
        float v = s[ct][r] * 0.125f;
        if (qi >= 0 && j >= 16 && (j-16) > qi) v = -1e30f;
        vals[ct] = v; mx = fmaxf(mx, v);
      }
      #pragma unroll
      for (int d=1; d<16; d<<=1) mx = fmaxf(mx, __shfl_xor(mx, d));
      float sum = 0.f;
      #pragma unroll
      for (int ct=0; ct<9; ++ct){ float e = expf(vals[ct]-mx); vals[ct] = e; sum += e; }
      #pragma unroll
      for (int d=1; d<16; d<<=1) sum += __shfl_xor(sum, d);
      const float inv = 1.f/sum;
      #pragma unroll
      for (int ct=0; ct<9; ++ct) Pl[w][(rsub+r)*160 + ct*16 + fr] = f2b(vals[ct]*inv);
    }
    #pragma unroll
    for (int oc=0; oc<4; ++oc){
      f32x4 o = (f32x4){0.f,0.f,0.f,0.f};
      #pragma unroll
      for (int ks=0; ks<5; ++ks){
        short8 pa = *(const short8*)&Pl[w][fr*160 + ks*32 + fkb];
        short8 vb = *(const short8*)&Vt[(oc*16+fr)*160 + ks*32 + fkb];
        o = __builtin_amdgcn_mfma_f32_16x16x32_bf16(pa, vb, o, 0,0,0);
      }
      #pragma unroll
      for (int r=0;r<4;++r)
        Ob[(size_t)(t0+rsub+r)*1024 + oc*16 + fr] = f2b(o[r]);
    }
  }
}

// ---------- LN helpers ----------
__device__ __forceinline__ void ln_stats(float s, float s2, float* red, int tid,
                                         float& mu, float& rstd)
{
  #pragma unroll
  for (int d=1; d<64; d<<=1){ s += __shfl_xor(s,d); s2 += __shfl_xor(s2,d); }
  if ((tid&63)==0){ red[tid>>6] = s; red[4+(tid>>6)] = s2; }
  __syncthreads();
  s  = red[0]+red[1]+red[2]+red[3];
  s2 = red[4]+red[5]+red[6]+red[7];
  mu = s * (1.f/1024.f);
  float var = s2*(1.f/1024.f) - mu*mu;
  rstd = rsqrtf(fmaxf(var,0.f) + 1e-5f);
}

// build z = concat(mem, emb[ids]) + pos (f32), and zn = LN(z) (bf16)
__global__ __launch_bounds__(256)
void buildz_ln(const float* __restrict__ mem, const int* __restrict__ ids,
               const float* __restrict__ emb, const float* __restrict__ pos,
               const float* __restrict__ gam, const float* __restrict__ bet,
               float* __restrict__ z, u16* __restrict__ out, int k)
{
  __shared__ float red[8];
  const int row = blockIdx.x;
  const int b = row / 144, t = row % 144;
  const int tid = threadIdx.x, c0 = tid*4;
  float v[4];
  if (t < 16){
    const f32x4 mv = *(const f32x4*)(mem + (size_t)(b*16+t)*1024 + c0);
    v[0]=mv[0]; v[1]=mv[1]; v[2]=mv[2]; v[3]=mv[3];
  } else {
    const int tok = ids[b*2048 + k*128 + (t-16)];
    const f32x4 e4 = *(const f32x4*)(emb + (size_t)tok*1024 + c0);
    v[0]=e4[0]; v[1]=e4[1]; v[2]=e4[2]; v[3]=e4[3];
  }
  const f32x4 p4 = *(const f32x4*)(pos + (size_t)t*1024 + c0);
  v[0]+=p4[0]; v[1]+=p4[1]; v[2]+=p4[2]; v[3]+=p4[3];
  f32x4 zz; zz[0]=v[0]; zz[1]=v[1]; zz[2]=v[2]; zz[3]=v[3];
  *(f32x4*)(z + (size_t)row*1024 + c0) = zz;
  float s = v[0]+v[1]+v[2]+v[3];
  float s2 = v[0]*v[0]+v[1]*v[1]+v[2]*v[2]+v[3]*v[3];
  float mu, rstd; ln_stats(s, s2, red, tid, mu, rstd);
  const f32x4 g4 = *(const f32x4*)(gam + c0);
  const f32x4 b4 = *(const f32x4*)(bet + c0);
  ushort4 o4;
  o4.x = f2b((v[0]-mu)*rstd*g4[0]+b4[0]);
  o4.y = f2b((v[1]-mu)*rstd*g4[1]+b4[1]);
  o4.z = f2b((v[2]-mu)*rstd*g4[2]+b4[2]);
  o4.w = f2b((v[3]-mu)*rstd*g4[3]+b4[3]);
  *(ushort4*)(out + (size_t)row*1024 + c0) = o4;
}

// LN over f32 source rows (remap=1: row -> b*144+16+i), bf16 out
__global__ __launch_bounds__(256)
void ln_f32(const float* __restrict__ src, const float* __restrict__ gam,
            const float* __restrict__ bet, u16* __restrict__ out, int remap)
{
  __shared__ float red[8];
  const int row = blockIdx.x;
  const int srow = remap ? ((row>>7)*144 + 16 + (row&127)) : row;
  const int tid = threadIdx.x, c0 = tid*4;
  const f32x4 xv = *(const f32x4*)(src + (size_t)srow*1024 + c0);
  float v[4] = {xv[0], xv[1], xv[2], xv[3]};
  float s = v[0]+v[1]+v[2]+v[3];
  float s2 = v[0]*v[0]+v[1]*v[1]+v[2]*v[2]+v[3]*v[3];
  float mu, rstd; ln_stats(s, s2, red, tid, mu, rstd);
  const f32x4 g4 = *(const f32x4*)(gam + c0);
  const f32x4 b4 = *(const f32x4*)(bet + c0);
  ushort4 o4;
  o4.x = f2b((v[0]-mu)*rstd*g4[0]+b4[0]);
  o4.y = f2b((v[1]-mu)*rstd*g4[1]+b4[1]);
  o4.z = f2b((v[2]-mu)*rstd*g4[2]+b4[2]);
  o4.w = f2b((v[3]-mu)*rstd*g4[3]+b4[3]);
  *(ushort4*)(out + (size_t)row*1024 + c0) = o4;
}

// kv = LN(concat(proj_mem(bf16 ws), enc_chunk(f32 input))), bf16 out
__global__ __launch_bounds__(256)
void ln_kv(const u16* __restrict__ pmem, const float* __restrict__ enc,
           const float* __restrict__ gam, const float* __restrict__ bet,
           u16* __restrict__ out, int k)
{
  __shared__ float red[8];
  const int row = blockIdx.x;
  const int b = row / 144, t = row % 144;
  const int tid = threadIdx.x, c0 = tid*4;
  float v[4];
  if (t < 16){
    const ushort4 x4 = *(const ushort4*)(pmem + (size_t)(b*16+t)*1024 + c0);
    v[0]=b2f(x4.x); v[1]=b2f(x4.y); v[2]=b2f(x4.z); v[3]=b2f(x4.w);
  } else {
    const f32x4 x4 = *(const f32x4*)(enc + ((size_t)b*2048 + k*128 + (t-16))*1024 + c0);
    v[0]=x4[0]; v[1]=x4[1]; v[2]=x4[2]; v[3]=x4[3];
  }
  float s = v[0]+v[1]+v[2]+v[3];
  float s2 = v[0]*v[0]+v[1]*v[1]+v[2]*v[2]+v[3]*v[3];
  float mu, rstd; ln_stats(s, s2, red, tid, mu, rstd);
  const f32x4 g4 = *(const f32x4*)(gam + c0);
  const f32x4 b4 = *(const f32x4*)(bet + c0);
  ushort4 o4;
  o4.x = f2b((v[0]-mu)*rstd*g4[0]+b4[0]);
  o4.y = f2b((v[1]-mu)*rstd*g4[1]+b4[1]);
  o4.z = f2b((v[2]-mu)*rstd*g4[2]+b4[2]);
  o4.w = f2b((v[3]-mu)*rstd*g4[3]+b4[3]);
  *(ushort4*)(out + (size_t)row*1024 + c0) = o4;
}

// mem_cand (z rows t<16) -> bf16 compact
__global__ __launch_bounds__(256)
void mc_cast(const float* __restrict__ z, u16* __restrict__ mcb)
{
  const int i = blockIdx.x*1024 + threadIdx.x*4;
  const int r = i >> 10, c = i & 1023;
  const int b = r >> 4, t = r & 15;
  const f32x4 zv = *(const f32x4*)(z + (size_t)(b*144+t)*1024 + c);
  ushort4 o4; o4.x=f2b(zv[0]); o4.y=f2b(zv[1]); o4.z=f2b(zv[2]); o4.w=f2b(zv[3]);
  *(ushort4*)(mcb + i) = o4;
}

// mem = (k==0) ? mem_cand : g*mem_cand + (1-g)*mem
__global__ __launch_bounds__(256)
void gate_apply(const float* __restrict__ z, const float* __restrict__ gate,
                float* __restrict__ mem, int k)
{
  const int i = blockIdx.x*1024 + threadIdx.x*4;
  const int r = i >> 10, c = i & 1023;
  const int b = r >> 4, t = r & 15;
  const f32x4 mc = *(const f32x4*)(z + (size_t)(b*144+t)*1024 + c);
  f32x4 out;
  if (k == 0){
    out = mc;
  } else {
    const f32x4 gg = *(const f32x4*)(gate + i);
    const f32x4 mo = *(const f32x4*)(mem + i);
    out[0] = gg[0]*mc[0] + (1.f-gg[0])*mo[0];
    out[1] = gg[1]*mc[1] + (1.f-gg[1])*mo[1];
    out[2] = gg[2]*mc[2] + (1.f-gg[2])*mo[2];
    out[3] = gg[3]*mc[3] + (1.f-gg[3])*mo[3];
  }
  *(f32x4*)(mem + i) = out;
}

// out[b, k*128+i, :] = z[b*144+16+i, :]  (F32 store — the verified fix)
__global__ __launch_bounds__(256)
void writeout(const float* __restrict__ z, float* __restrict__ out, int k)
{
  const int row = blockIdx.x;          // 0..2047
  const int b = row >> 7, t = row & 127;
  const int c0 = threadIdx.x*4;
  const f32x4 zv = *(const f32x4*)(z + (size_t)(b*144+16+t)*1024 + c0);
  *(f32x4*)(out + ((size_t)b*2048 + k*128 + t)*1024 + c0) = zv;
}

extern "C" void kernel_launch(void* const* d_in, const int* in_sizes, int n_in,
                              void* d_out, int out_size, void* d_ws, size_t ws_size,
                              hipStream_t stream)
{
  const int*   in_res   = (const int*)d_in[0];
  const float* enc_out  = (const float*)d_in[1];
  const float* enc_mem  = (const float*)d_in[2];
  const float* emb      = (const float*)d_in[3];
  const float* Wmem     = (const float*)d_in[4];
  const float* bmem     = (const float*)d_in[5];
  const float* pos      = (const float*)d_in[6];
  const float* Wqkv_s   = (const float*)d_in[7];
  const float* bqkv_s   = (const float*)d_in[8];
  const float* Wo_s     = (const float*)d_in[9];
  const float* bo_s     = (const float*)d_in[10];
  const float* g_la     = (const float*)d_in[11];
  const float* b_la     = (const float*)d_in[12];
  const float* W1       = (const float*)d_in[13];
  const float* b1       = (const float*)d_in[14];
  const float* W2       = (const float*)d_in[15];
  const float* b2       = (const float*)d_in[16];
  const float* g_lf     = (const float*)d_in[17];
  const float* b_lf     = (const float*)d_in[18];
  const float* Wencm    = (const float*)d_in[19];
  const float* bencm    = (const float*)d_in[20];
  const float* Wqkv_c   = (const float*)d_in[21];
  const float* bqkv_c   = (const float*)d_in[22];
  const float* Wo_c     = (const float*)d_in[23];
  const float* bo_c     = (const float*)d_in[24];
  const float* g_lq     = (const float*)d_in[25];
  const float* b_lq     = (const float*)d_in[26];
  const float* g_lkv    = (const float*)d_in[27];
  const float* b_lkv    = (const float*)d_in[28];
  const float* W1c      = (const float*)d_in[29];
  const float* b1c      = (const float*)d_in[30];
  const float* W2c      = (const float*)d_in[31];
  const float* b2c      = (const float*)d_in[32];
  const float* g_lfc    = (const float*)d_in[33];
  const float* b_lfc    = (const float*)d_in[34];
  const float* Wg       = (const float*)d_in[35];
  const float* bg       = (const float*)d_in[36];

  char* ws = (char*)d_ws;
  size_t off = 0;
  auto alloc = [&](size_t bytes)->void*{
    void* p = ws + off; off += (bytes + 255) & ~(size_t)255; return p;
  };
  // activations
  float* z    = (float*)alloc((size_t)2304*1024*4);
  u16*  lnbuf = (u16*) alloc((size_t)2304*1024*2);
  u16*  qkv   = (u16*) alloc((size_t)2304*3072*2);
  u16*  attnb = (u16*) alloc((size_t)2304*1024*2);
  u16*  mid   = (u16*) alloc((size_t)2304*4096*2);
  u16*  kvb   = (u16*) alloc((size_t)2304*1024*2);
  float* memf = (float*)alloc((size_t)256*1024*4);
  u16*  pmem  = (u16*) alloc((size_t)256*1024*2);
  u16*  mcb   = (u16*) alloc((size_t)256*1024*2);
  float* gate = (float*)alloc((size_t)256*1024*4);
  // bf16 weight copies
  const int DD = 1024*1024, D3 = 3*1024*1024, DFD = 4096*1024;
  u16* wWmem   = (u16*)alloc((size_t)DD*2);
  u16* wWqkv_s = (u16*)alloc((size_t)D3*2);
  u16* wWo_s   = (u16*)alloc((size_t)DD*2);
  u16* wW1     = (u16*)alloc((size_t)DFD*2);
  u16* wW2     = (u16*)alloc((size_t)DFD*2);
  u16* wWencm  = (u16*)alloc((size_t)DD*2);
  u16* wWqkv_c = (u16*)alloc((size_t)D3*2);
  u16* wWo_c   = (u16*)alloc((size_t)DD*2);
  u16* wW1c    = (u16*)alloc((size_t)DFD*2);
  u16* wW2c    = (u16*)alloc((size_t)DFD*2);
  u16* wWg     = (u16*)alloc((size_t)DD*2);
  u16* encmb   = (u16*)alloc((size_t)256*1024*2);

  u16* qc  = qkv;
  u16* kvc = qkv + (size_t)2048*1024;
  float* outf = (float*)d_out;

  dim3 blk(256);
  // prologue: weights -> bf16
  castk<<<DD/1024,  blk, 0, stream>>>(Wmem,   wWmem,   DD);
  castk<<<D3/1024,  blk, 0, stream>>>(Wqkv_s, wWqkv_s, D3);
  castk<<<DD/1024,  blk, 0, stream>>>(Wo_s,   wWo_s,   DD);
  castk<<<DFD/1024, blk, 0, stream>>>(W1,     wW1,     DFD);
  castk<<<DFD/1024, blk, 0, stream>>>(W2,     wW2,     DFD);
  castk<<<DD/1024,  blk, 0, stream>>>(Wencm,  wWencm,  DD);
  castk<<<D3/1024,  blk, 0, stream>>>(Wqkv_c, wWqkv_c, D3);
  castk<<<DD/1024,  blk, 0, stream>>>(Wo_c,   wWo_c,   DD);
  castk<<<DFD/1024, blk, 0, stream>>>(W1c,    wW1c,    DFD);
  castk<<<DFD/1024, blk, 0, stream>>>(W2c,    wW2c,    DFD);
  castk<<<DD/1024,  blk, 0, stream>>>(Wg,     wWg,     DD);
  castk<<<256,      blk, 0, stream>>>(enc_mem, encmb,  256*1024);

  // prologue: mem0 (f32) and proj_mem (bf16)
  gemm_bt<4><<<dim3(8,2), blk, 0, stream>>>(encmb, wWmem,  bmem,  memf, 1024, 1024, 0);
  gemm_bt<0><<<dim3(8,2), blk, 0, stream>>>(encmb, wWencm, bencm, pmem, 1024, 1024, 0);

  for (int k = 0; k < 16; ++k){
    buildz_ln<<<2304, blk, 0, stream>>>(memf, in_res, emb, pos, g_la, b_la, z, lnbuf, k);
    gemm_bt<0><<<dim3(24,18), blk, 0, stream>>>(lnbuf, wWqkv_s, bqkv_s, qkv, 3072, 1024, 0);
    attn_kernel<<<256, blk, 0, stream>>>(qkv, 3072, qkv+1024, qkv+2048, 3072, attnb, 144, -16);
    gemm_bt<2><<<dim3(8,18), blk, 0, stream>>>(attnb, wWo_s, bo_s, z, 1024, 1024, 0);
    ln_f32<<<2304, blk, 0, stream>>>(z, g_lf, b_lf, lnbuf, 0);
    gemm_bt<1><<<dim3(32,18), blk, 0, stream>>>(lnbuf, wW1, b1, mid, 4096, 1024, 0);
    gemm_bt<2><<<dim3(8,18), blk, 0, stream>>>(mid, wW2, b2, z, 1024, 4096, 0);
    // cross block
    ln_f32<<<2048, blk, 0, stream>>>(z, g_lq, b_lq, lnbuf, 1);
    gemm_bt<0><<<dim3(8,16), blk, 0, stream>>>(lnbuf, wWqkv_c, bqkv_c, qc, 1024, 1024, 0);
    ln_kv<<<2304, blk, 0, stream>>>(pmem, enc_out, g_lkv, b_lkv, kvb, k);
    gemm_bt<0><<<dim3(16,18), blk, 0, stream>>>(kvb, wWqkv_c + (size_t)1024*1024,
                                                bqkv_c + 1024, kvc, 2048, 1024, 0);
    attn_kernel<<<256, blk, 0, stream>>>(qc, 1024, kvc, kvc+1024, 2048, attnb, 128, 0);
    gemm_bt<2><<<dim3(8,16), blk, 0, stream>>>(attnb, wWo_c, bo_c, z, 1024, 1024, 1);
    ln_f32<<<2048, blk, 0, stream>>>(z, g_lfc, b_lfc, lnbuf, 1);
    gemm_bt<1><<<dim3(32,16), blk, 0, stream>>>(lnbuf, wW1c, b1c, mid, 4096, 1024, 0);
    gemm_bt<2><<<dim3(8,16), blk, 0, stream>>>(mid, wW2c, b2c, z, 1024, 4096, 1);
    writeout<<<2048, blk, 0, stream>>>(z, outf, k);
    // memory gate
    mc_cast<<<256, blk, 0, stream>>>(z, mcb);
    gemm_bt<3><<<dim3(8,2), blk, 0, stream>>>(mcb, wWg, bg, gate, 1024, 1024, 0);
    gate_apply<<<256, blk, 0, stream>>>(z, gate, memf, k);
  }
}

// Round 23
// 6451.784 us; speedup vs baseline: 8.3805x; 1.1274x over previous
//
#include <hip/hip_runtime.h>
#include <hip/hip_bf16.h>

#define AS1 __attribute__((address_space(1)))
#define AS3 __attribute__((address_space(3)))

typedef unsigned short u16;
typedef __attribute__((ext_vector_type(8))) short short8;
typedef __attribute__((ext_vector_type(4))) float f32x4;

__device__ __forceinline__ float b2f(u16 u){ return __uint_as_float(((unsigned)u)<<16); }
__device__ __forceinline__ u16 f2b(float f){
  unsigned x = __float_as_uint(f);
  return (u16)((x + 0x7FFFu + ((x>>16)&1u)) >> 16);
}

// ---------- f32 -> bf16 cast ----------
__global__ __launch_bounds__(256)
void castk(const float* __restrict__ src, u16* __restrict__ dst, int n)
{
  const int i = (blockIdx.x*256 + threadIdx.x)*4;
  if (i < n){
    const f32x4 v = *(const f32x4*)(src + i);
    ushort4 o; o.x=f2b(v[0]); o.y=f2b(v[1]); o.z=f2b(v[2]); o.w=f2b(v[3]);
    *(ushort4*)(dst + i) = o;
  }
}

// ---------- MFMA GEMM: C(M,N) = A(M,K) @ W(N,K)^T + bias ----------
// MODE 0: bf16 out; 1: bf16 relu; 2: f32 residual atomicAdd (ld 1024, opt remap; split-K via gridDim.z);
// MODE 3: f32 sigmoid; 4: f32 out
template<int MODE>
__global__ __launch_bounds__(256)
void gemm_bt(const u16* __restrict__ A, const u16* __restrict__ W,
             const float* __restrict__ bias, void* __restrict__ Cout,
             int N, int K, int remap)
{
  __shared__ u16 Al[128*64];
  __shared__ u16 Bl[128*64];
  const int tid  = threadIdx.x;
  const int lane = tid & 63;
  const int w    = tid >> 6;
  const int wr = (w>>1)*64, wc = (w&1)*64;
  const int fr = lane & 15;
  const int fk = (lane>>4)*8;
  const int r8 = tid >> 3;
  const int c8 = (tid & 7)*8;
  const u16* ag = A + (size_t)(blockIdx.y*128 + r8)*K + c8;
  const u16* bg = W + (size_t)(blockIdx.x*128 + r8)*K + c8;
  u16* al = &Al[r8*64 + c8];
  u16* bl = &Bl[r8*64 + c8];

  const int Klen = K / gridDim.z;
  const int kb   = Klen * blockIdx.z;

  f32x4 acc[4][4];
  #pragma unroll
  for (int m=0;m<4;++m)
    #pragma unroll
    for (int n=0;n<4;++n) acc[m][n] = (f32x4){0.f,0.f,0.f,0.f};

  for (int kt=kb; kt<kb+Klen; kt+=64){
    #pragma unroll
    for (int r=0;r<4;++r){
      __builtin_amdgcn_global_load_lds((const AS1 void*)(ag + (size_t)(r*32)*K + kt),
                                       (AS3 void*)(al + r*32*64), 16, 0, 0);
      __builtin_amdgcn_global_load_lds((const AS1 void*)(bg + (size_t)(r*32)*K + kt),
                                       (AS3 void*)(bl + r*32*64), 16, 0, 0);
    }
    __syncthreads();
    #pragma unroll
    for (int kk=0; kk<64; kk+=32){
      short8 a[4], b[4];
      #pragma unroll
      for (int m=0;m<4;++m) a[m] = *(const short8*)&Al[(wr+m*16+fr)*64 + kk + fk];
      #pragma unroll
      for (int n=0;n<4;++n) b[n] = *(const short8*)&Bl[(wc+n*16+fr)*64 + kk + fk];
      #pragma unroll
      for (int m=0;m<4;++m)
        #pragma unroll
        for (int n=0;n<4;++n)
          acc[m][n] = __builtin_amdgcn_mfma_f32_16x16x32_bf16(a[m], b[n], acc[m][n], 0, 0, 0);
    }
    __syncthreads();
  }

  const int rsub = (lane>>4)*4;
  #pragma unroll
  for (int n=0;n<4;++n){
    const int col = blockIdx.x*128 + wc + n*16 + fr;
    const float bv = (MODE==2 && blockIdx.z != 0) ? 0.f : bias[col];
    #pragma unroll
    for (int m=0;m<4;++m){
      const int row0 = blockIdx.y*128 + wr + m*16 + rsub;
      #pragma unroll
      for (int r=0;r<4;++r){
        const int row = row0 + r;
        float v = acc[m][n][r] + bv;
        if (MODE==0) ((u16*)Cout)[(size_t)row*N + col] = f2b(v);
        else if (MODE==1) ((u16*)Cout)[(size_t)row*N + col] = f2b(fmaxf(v,0.f));
        else if (MODE==2){
          const int orow = remap ? ((row>>7)*144 + 16 + (row&127)) : row;
          atomicAdd((float*)Cout + (size_t)orow*1024 + col, v);
        }
        else if (MODE==3) ((float*)Cout)[(size_t)row*N + col] = 1.f/(1.f+expf(-v));
        else ((float*)Cout)[(size_t)row*N + col] = v;
      }
    }
  }
}

// ---------- MFMA attention: per-(b,h) block; KV rows j<16 from "mem" src, j>=16 from "enc" src ----------
__global__ __launch_bounds__(256)
void attn_kernel(const u16* __restrict__ Qp, int ldq,
                 const u16* __restrict__ Km, const u16* __restrict__ Vm, int ldm, size_t bsm,
                 const u16* __restrict__ Ke, const u16* __restrict__ Ve, int lde, size_t bse,
                 u16* __restrict__ Op, int nq, int qoff)
{
  __shared__ u16 Kl[144*64];
  __shared__ u16 Vt[64*160];
  __shared__ u16 Pl[4][16*160];
  const int tid = threadIdx.x, lane = tid & 63, w = tid >> 6;
  const int b = blockIdx.x >> 4, h = blockIdx.x & 15;
  const u16* Qb = Qp + (size_t)(b*nq)*ldq + h*64;
  u16* Ob = Op + (size_t)(b*nq)*1024 + h*64;

  for (int i = tid*4; i < 64*160; i += 1024){ ushort4 zz = {0,0,0,0}; *(ushort4*)&Vt[i] = zz; }
  for (int i = tid*4; i < 4*16*160; i += 1024){ ushort4 zz = {0,0,0,0}; *(ushort4*)&Pl[0][i] = zz; }
  __syncthreads();

  for (int idx = tid*4; idx < 144*64; idx += 1024){
    const int j = idx >> 6, c = idx & 63;
    const u16* Kr = (j < 16) ? (Km + (size_t)b*bsm + (size_t)j*ldm + h*64)
                             : (Ke + (size_t)b*bse + (size_t)(j-16)*lde + h*64);
    const u16* Vr = (j < 16) ? (Vm + (size_t)b*bsm + (size_t)j*ldm + h*64)
                             : (Ve + (size_t)b*bse + (size_t)(j-16)*lde + h*64);
    ushort4 kk4 = *(const ushort4*)(Kr + c);
    *(ushort4*)&Kl[j*64 + c] = kk4;
    ushort4 vv4 = *(const ushort4*)(Vr + c);
    Vt[(c+0)*160 + j] = vv4.x; Vt[(c+1)*160 + j] = vv4.y;
    Vt[(c+2)*160 + j] = vv4.z; Vt[(c+3)*160 + j] = vv4.w;
  }
  __syncthreads();

  const int fr = lane & 15;
  const int fkb = (lane>>4)*8;
  const int rsub = (lane>>4)*4;
  const int ntiles = nq >> 4;
  for (int qt = w; qt < ntiles; qt += 4){
    const int t0 = qt*16;
    short8 qa0 = *(const short8*)(Qb + (size_t)(t0+fr)*ldq + fkb);
    short8 qa1 = *(const short8*)(Qb + (size_t)(t0+fr)*ldq + 32 + fkb);
    f32x4 s[9];
    #pragma unroll
    for (int ct=0; ct<9; ++ct){
      f32x4 z = (f32x4){0.f,0.f,0.f,0.f};
      short8 b0 = *(const short8*)&Kl[(ct*16+fr)*64 + fkb];
      z = __builtin_amdgcn_mfma_f32_16x16x32_bf16(qa0, b0, z, 0,0,0);
      short8 b1 = *(const short8*)&Kl[(ct*16+fr)*64 + 32 + fkb];
      z = __builtin_amdgcn_mfma_f32_16x16x32_bf16(qa1, b1, z, 0,0,0);
      s[ct] = z;
    }
    #pragma unroll
    for (int r=0;r<4;++r){
      const int t = t0 + rsub + r;
      const int qi = t + qoff;
      float vals[9];
      float mx = -1e30f;
      #pragma unroll
      for (int ct=0; ct<9; ++ct){
        const int j = ct*16 + fr;
        float v = s[ct][r] * 0.125f;
        if (qi >= 0 && j >= 16 && (j-16) > qi) v = -1e30f;
        vals[ct] = v; mx = fmaxf(mx, v);
      }
      #pragma unroll
      for (int d=1; d<16; d<<=1) mx = fmaxf(mx, __shfl_xor(mx, d));
      float sum = 0.f;
      #pragma unroll
      for (int ct=0; ct<9; ++ct){ float e = expf(vals[ct]-mx); vals[ct] = e; sum += e; }
      #pragma unroll
      for (int d=1; d<16; d<<=1) sum += __shfl_xor(sum, d);
      const float inv = 1.f/sum;
      #pragma unroll
      for (int ct=0; ct<9; ++ct) Pl[w][(rsub+r)*160 + ct*16 + fr] = f2b(vals[ct]*inv);
    }
    #pragma unroll
    for (int oc=0; oc<4; ++oc){
      f32x4 o = (f32x4){0.f,0.f,0.f,0.f};
      #pragma unroll
      for (int ks=0; ks<5; ++ks){
        short8 pa = *(const short8*)&Pl[w][fr*160 + ks*32 + fkb];
        short8 vb = *(const short8*)&Vt[(oc*16+fr)*160 + ks*32 + fkb];
        o = __builtin_amdgcn_mfma_f32_16x16x32_bf16(pa, vb, o, 0,0,0);
      }
      #pragma unroll
      for (int r=0;r<4;++r)
        Ob[(size_t)(t0+rsub+r)*1024 + oc*16 + fr] = f2b(o[r]);
    }
  }
}

// ---------- LN helpers ----------
__device__ __forceinline__ void ln_stats(float s, float s2, float* red, int tid,
                                         float& mu, float& rstd)
{
  #pragma unroll
  for (int d=1; d<64; d<<=1){ s += __shfl_xor(s,d); s2 += __shfl_xor(s2,d); }
  if ((tid&63)==0){ red[tid>>6] = s; red[4+(tid>>6)] = s2; }
  __syncthreads();
  s  = red[0]+red[1]+red[2]+red[3];
  s2 = red[4]+red[5]+red[6]+red[7];
  mu = s * (1.f/1024.f);
  float var = s2*(1.f/1024.f) - mu*mu;
  rstd = rsqrtf(fmaxf(var,0.f) + 1e-5f);
}

__global__ __launch_bounds__(256)
void buildz_ln(const float* __restrict__ mem, const int* __restrict__ ids,
               const float* __restrict__ emb, const float* __restrict__ pos,
               const float* __restrict__ gam, const float* __restrict__ bet,
               float* __restrict__ z, u16* __restrict__ out, int k)
{
  __shared__ float red[8];
  const int row = blockIdx.x;
  const int b = row / 144, t = row % 144;
  const int tid = threadIdx.x, c0 = tid*4;
  float v[4];
  if (t < 16){
    const f32x4 mv = *(const f32x4*)(mem + (size_t)(b*16+t)*1024 + c0);
    v[0]=mv[0]; v[1]=mv[1]; v[2]=mv[2]; v[3]=mv[3];
  } else {
    const int tok = ids[b*2048 + k*128 + (t-16)];
    const f32x4 e4 = *(const f32x4*)(emb + (size_t)tok*1024 + c0);
    v[0]=e4[0]; v[1]=e4[1]; v[2]=e4[2]; v[3]=e4[3];
  }
  const f32x4 p4 = *(const f32x4*)(pos + (size_t)t*1024 + c0);
  v[0]+=p4[0]; v[1]+=p4[1]; v[2]+=p4[2]; v[3]+=p4[3];
  f32x4 zz; zz[0]=v[0]; zz[1]=v[1]; zz[2]=v[2]; zz[3]=v[3];
  *(f32x4*)(z + (size_t)row*1024 + c0) = zz;
  float s = v[0]+v[1]+v[2]+v[3];
  float s2 = v[0]*v[0]+v[1]*v[1]+v[2]*v[2]+v[3]*v[3];
  float mu, rstd; ln_stats(s, s2, red, tid, mu, rstd);
  const f32x4 g4 = *(const f32x4*)(gam + c0);
  const f32x4 b4 = *(const f32x4*)(bet + c0);
  ushort4 o4;
  o4.x = f2b((v[0]-mu)*rstd*g4[0]+b4[0]);
  o4.y = f2b((v[1]-mu)*rstd*g4[1]+b4[1]);
  o4.z = f2b((v[2]-mu)*rstd*g4[2]+b4[2]);
  o4.w = f2b((v[3]-mu)*rstd*g4[3]+b4[3]);
  *(ushort4*)(out + (size_t)row*1024 + c0) = o4;
}

__global__ __launch_bounds__(256)
void ln_f32(const float* __restrict__ src, const float* __restrict__ gam,
            const float* __restrict__ bet, u16* __restrict__ out, int remap)
{
  __shared__ float red[8];
  const int row = blockIdx.x;
  const int srow = remap ? ((row>>7)*144 + 16 + (row&127)) : row;
  const int tid = threadIdx.x, c0 = tid*4;
  const f32x4 xv = *(const f32x4*)(src + (size_t)srow*1024 + c0);
  float v[4] = {xv[0], xv[1], xv[2], xv[3]};
  float s = v[0]+v[1]+v[2]+v[3];
  float s2 = v[0]*v[0]+v[1]*v[1]+v[2]*v[2]+v[3]*v[3];
  float mu, rstd; ln_stats(s, s2, red, tid, mu, rstd);
  const f32x4 g4 = *(const f32x4*)(gam + c0);
  const f32x4 b4 = *(const f32x4*)(bet + c0);
  ushort4 o4;
  o4.x = f2b((v[0]-mu)*rstd*g4[0]+b4[0]);
  o4.y = f2b((v[1]-mu)*rstd*g4[1]+b4[1]);
  o4.z = f2b((v[2]-mu)*rstd*g4[2]+b4[2]);
  o4.w = f2b((v[3]-mu)*rstd*g4[3]+b4[3]);
  *(ushort4*)(out + (size_t)row*1024 + c0) = o4;
}

// LN over bf16 source rows (for proj_mem)
__global__ __launch_bounds__(256)
void ln_b16(const u16* __restrict__ src, const float* __restrict__ gam,
            const float* __restrict__ bet, u16* __restrict__ out)
{
  __shared__ float red[8];
  const int row = blockIdx.x;
  const int tid = threadIdx.x, c0 = tid*4;
  const ushort4 x4 = *(const ushort4*)(src + (size_t)row*1024 + c0);
  float v[4] = {b2f(x4.x), b2f(x4.y), b2f(x4.z), b2f(x4.w)};
  float s = v[0]+v[1]+v[2]+v[3];
  float s2 = v[0]*v[0]+v[1]*v[1]+v[2]*v[2]+v[3]*v[3];
  float mu, rstd; ln_stats(s, s2, red, tid, mu, rstd);
  const f32x4 g4 = *(const f32x4*)(gam + c0);
  const f32x4 b4 = *(const f32x4*)(bet + c0);
  ushort4 o4;
  o4.x = f2b((v[0]-mu)*rstd*g4[0]+b4[0]);
  o4.y = f2b((v[1]-mu)*rstd*g4[1]+b4[1]);
  o4.z = f2b((v[2]-mu)*rstd*g4[2]+b4[2]);
  o4.w = f2b((v[3]-mu)*rstd*g4[3]+b4[3]);
  *(ushort4*)(out + (size_t)row*1024 + c0) = o4;
}

__global__ __launch_bounds__(256)
void mc_cast(const float* __restrict__ z, u16* __restrict__ mcb)
{
  const int i = blockIdx.x*1024 + threadIdx.x*4;
  const int r = i >> 10, c = i & 1023;
  const int b = r >> 4, t = r & 15;
  const f32x4 zv = *(const f32x4*)(z + (size_t)(b*144+t)*1024 + c);
  ushort4 o4; o4.x=f2b(zv[0]); o4.y=f2b(zv[1]); o4.z=f2b(zv[2]); o4.w=f2b(zv[3]);
  *(ushort4*)(mcb + i) = o4;
}

__global__ __launch_bounds__(256)
void gate_apply(const float* __restrict__ z, const float* __restrict__ gate,
                float* __restrict__ mem, int k)
{
  const int i = blockIdx.x*1024 + threadIdx.x*4;
  const int r = i >> 10, c = i & 1023;
  const int b = r >> 4, t = r & 15;
  const f32x4 mc = *(const f32x4*)(z + (size_t)(b*144+t)*1024 + c);
  f32x4 out;
  if (k == 0){
    out = mc;
  } else {
    const f32x4 gg = *(const f32x4*)(gate + i);
    const f32x4 mo = *(const f32x4*)(mem + i);
    out[0] = gg[0]*mc[0] + (1.f-gg[0])*mo[0];
    out[1] = gg[1]*mc[1] + (1.f-gg[1])*mo[1];
    out[2] = gg[2]*mc[2] + (1.f-gg[2])*mo[2];
    out[3] = gg[3]*mc[3] + (1.f-gg[3])*mo[3];
  }
  *(f32x4*)(mem + i) = out;
}

// out[b, k*128+i, :] = z[b*144+16+i, :]  (f32 store)
__global__ __launch_bounds__(256)
void writeout(const float* __restrict__ z, float* __restrict__ out, int k)
{
  const int row = blockIdx.x;
  const int b = row >> 7, t = row & 127;
  const int c0 = threadIdx.x*4;
  const f32x4 zv = *(const f32x4*)(z + (size_t)(b*144+16+t)*1024 + c0);
  *(f32x4*)(out + ((size_t)b*2048 + k*128 + t)*1024 + c0) = zv;
}

extern "C" void kernel_launch(void* const* d_in, const int* in_sizes, int n_in,
                              void* d_out, int out_size, void* d_ws, size_t ws_size,
                              hipStream_t stream)
{
  const int*   in_res   = (const int*)d_in[0];
  const float* enc_out  = (const float*)d_in[1];
  const float* enc_mem  = (const float*)d_in[2];
  const float* emb      = (const float*)d_in[3];
  const float* Wmem     = (const float*)d_in[4];
  const float* bmem     = (const float*)d_in[5];
  const float* pos      = (const float*)d_in[6];
  const float* Wqkv_s   = (const float*)d_in[7];
  const float* bqkv_s   = (const float*)d_in[8];
  const float* Wo_s     = (const float*)d_in[9];
  const float* bo_s     = (const float*)d_in[10];
  const float* g_la     = (const float*)d_in[11];
  const float* b_la     = (const float*)d_in[12];
  const float* W1       = (const float*)d_in[13];
  const float* b1       = (const float*)d_in[14];
  const float* W2       = (const float*)d_in[15];
  const float* b2       = (const float*)d_in[16];
  const float* g_lf     = (const float*)d_in[17];
  const float* b_lf     = (const float*)d_in[18];
  const float* Wencm    = (const float*)d_in[19];
  const float* bencm    = (const float*)d_in[20];
  const float* Wqkv_c   = (const float*)d_in[21];
  const float* bqkv_c   = (const float*)d_in[22];
  const float* Wo_c     = (const float*)d_in[23];
  const float* bo_c     = (const float*)d_in[24];
  const float* g_lq     = (const float*)d_in[25];
  const float* b_lq     = (const float*)d_in[26];
  const float* g_lkv    = (const float*)d_in[27];
  const float* b_lkv    = (const float*)d_in[28];
  const float* W1c      = (const float*)d_in[29];
  const float* b1c      = (const float*)d_in[30];
  const float* W2c      = (const float*)d_in[31];
  const float* b2c      = (const float*)d_in[32];
  const float* g_lfc    = (const float*)d_in[33];
  const float* b_lfc    = (const float*)d_in[34];
  const float* Wg       = (const float*)d_in[35];
  const float* bg       = (const float*)d_in[36];

  char* ws = (char*)d_ws;
  size_t off = 0;
  auto alloc = [&](size_t bytes)->void*{
    void* p = ws + off; off += (bytes + 255) & ~(size_t)255; return p;
  };
  // activations
  float* z     = (float*)alloc((size_t)2304*1024*4);
  u16*  lnbuf  = (u16*) alloc((size_t)2304*1024*2);
  u16*  qkv    = (u16*) alloc((size_t)2304*3072*2);
  u16*  attnb  = (u16*) alloc((size_t)2304*1024*2);
  u16*  mid    = (u16*) alloc((size_t)2304*4096*2);
  float* memf  = (float*)alloc((size_t)256*1024*4);
  u16*  pmem   = (u16*) alloc((size_t)256*1024*2);
  u16*  mcb    = (u16*) alloc((size_t)256*1024*2);
  float* gate  = (float*)alloc((size_t)256*1024*4);
  u16*  kvmln  = (u16*) alloc((size_t)256*1024*2);     // LN(proj_mem)
  u16*  kvmem  = (u16*) alloc((size_t)256*2048*2);     // K/V for mem rows
  u16*  kveln  = (u16*) alloc((size_t)32768*1024*2);   // LN(enc_out), 64 MB
  // bf16 weight copies
  const int DD = 1024*1024, D3 = 3*1024*1024, DFD = 4096*1024;
  u16* wWmem   = (u16*)alloc((size_t)DD*2);
  u16* wWqkv_s = (u16*)alloc((size_t)D3*2);
  u16* wWo_s   = (u16*)alloc((size_t)DD*2);
  u16* wW1     = (u16*)alloc((size_t)DFD*2);
  u16* wW2     = (u16*)alloc((size_t)DFD*2);
  u16* wWencm  = (u16*)alloc((size_t)DD*2);
  u16* wWqkv_c = (u16*)alloc((size_t)D3*2);
  u16* wWo_c   = (u16*)alloc((size_t)DD*2);
  u16* wW1c    = (u16*)alloc((size_t)DFD*2);
  u16* wW2c    = (u16*)alloc((size_t)DFD*2);
  u16* wWg     = (u16*)alloc((size_t)DD*2);
  u16* encmb   = (u16*)alloc((size_t)256*1024*2);

  u16* qc  = qkv;
  float* outf = (float*)d_out;
  u16*  kvenc = (u16*)d_out;   // 32768 x 2048 bf16 == 32768 x 1024 f32 bytes

  dim3 blk(256);
  // weights -> bf16
  castk<<<DD/1024,  blk, 0, stream>>>(Wmem,   wWmem,   DD);
  castk<<<D3/1024,  blk, 0, stream>>>(Wqkv_s, wWqkv_s, D3);
  castk<<<DD/1024,  blk, 0, stream>>>(Wo_s,   wWo_s,   DD);
  castk<<<DFD/1024, blk, 0, stream>>>(W1,     wW1,     DFD);
  castk<<<DFD/1024, blk, 0, stream>>>(W2,     wW2,     DFD);
  castk<<<DD/1024,  blk, 0, stream>>>(Wencm,  wWencm,  DD);
  castk<<<D3/1024,  blk, 0, stream>>>(Wqkv_c, wWqkv_c, D3);
  castk<<<DD/1024,  blk, 0, stream>>>(Wo_c,   wWo_c,   DD);
  castk<<<DFD/1024, blk, 0, stream>>>(W1c,    wW1c,    DFD);
  castk<<<DFD/1024, blk, 0, stream>>>(W2c,    wW2c,    DFD);
  castk<<<DD/1024,  blk, 0, stream>>>(Wg,     wWg,     DD);
  castk<<<256,      blk, 0, stream>>>(enc_mem, encmb,  256*1024);

  // mem0 (f32) and proj_mem (bf16)
  gemm_bt<4><<<dim3(8,2), blk, 0, stream>>>(encmb, wWmem,  bmem,  memf, 1024, 1024, 0);
  gemm_bt<0><<<dim3(8,2), blk, 0, stream>>>(encmb, wWencm, bencm, pmem, 1024, 1024, 0);

  // hoisted KV: LN of all enc_out rows + proj_mem rows, then one big KV GEMM
  ln_f32<<<32768, blk, 0, stream>>>(enc_out, g_lkv, b_lkv, kveln, 0);
  ln_b16<<<256,   blk, 0, stream>>>(pmem, g_lkv, b_lkv, kvmln);
  gemm_bt<0><<<dim3(16,256), blk, 0, stream>>>(kveln, wWqkv_c + (size_t)1024*1024,
                                               bqkv_c + 1024, kvenc, 2048, 1024, 0);
  gemm_bt<0><<<dim3(16,2),   blk, 0, stream>>>(kvmln, wWqkv_c + (size_t)1024*1024,
                                               bqkv_c + 1024, kvmem, 2048, 1024, 0);

  const size_t bsm_c = (size_t)16*2048;     // kvmem batch stride
  const size_t bse_c = (size_t)2048*2048;   // kvenc batch stride
  const size_t bss   = (size_t)144*3072;    // self qkv batch stride

  for (int k = 0; k < 16; ++k){
    buildz_ln<<<2304, blk, 0, stream>>>(memf, in_res, emb, pos, g_la, b_la, z, lnbuf, k);
    gemm_bt<0><<<dim3(24,18), blk, 0, stream>>>(lnbuf, wWqkv_s, bqkv_s, qkv, 3072, 1024, 0);
    attn_kernel<<<256, blk, 0, stream>>>(qkv, 3072,
                                         qkv+1024, qkv+2048, 3072, bss,
                                         qkv+1024+(size_t)16*3072, qkv+2048+(size_t)16*3072, 3072, bss,
                                         attnb, 144, -16);
    gemm_bt<2><<<dim3(8,18,2), blk, 0, stream>>>(attnb, wWo_s, bo_s, z, 1024, 1024, 0);
    ln_f32<<<2304, blk, 0, stream>>>(z, g_lf, b_lf, lnbuf, 0);
    gemm_bt<1><<<dim3(32,18), blk, 0, stream>>>(lnbuf, wW1, b1, mid, 4096, 1024, 0);
    gemm_bt<2><<<dim3(8,18,4), blk, 0, stream>>>(mid, wW2, b2, z, 1024, 4096, 0);
    // cross block
    ln_f32<<<2048, blk, 0, stream>>>(z, g_lq, b_lq, lnbuf, 1);
    gemm_bt<0><<<dim3(8,16), blk, 0, stream>>>(lnbuf, wWqkv_c, bqkv_c, qc, 1024, 1024, 0);
    attn_kernel<<<256, blk, 0, stream>>>(qc, 1024,
                                         kvmem, kvmem+1024, 2048, bsm_c,
                                         kvenc + (size_t)k*128*2048, kvenc + (size_t)k*128*2048 + 1024, 2048, bse_c,
                                         attnb, 128, 0);
    gemm_bt<2><<<dim3(8,16,2), blk, 0, stream>>>(attnb, wWo_c, bo_c, z, 1024, 1024, 1);
    ln_f32<<<2048, blk, 0, stream>>>(z, g_lfc, b_lfc, lnbuf, 1);
    gemm_bt<1><<<dim3(32,16), blk, 0, stream>>>(lnbuf, wW1c, b1c, mid, 4096, 1024, 0);
    gemm_bt<2><<<dim3(8,16,4), blk, 0, stream>>>(mid, wW2c, b2c, z, 1024, 4096, 1);
    writeout<<<2048, blk, 0, stream>>>(z, outf, k);
    // memory gate
    mc_cast<<<256, blk, 0, stream>>>(z, mcb);
    gemm_bt<3><<<dim3(8,2), blk, 0, stream>>>(mcb, wWg, bg, gate, 1024, 1024, 0);
    gate_apply<<<256, blk, 0, stream>>>(z, gate, memf, k);
  }
}

// Round 24
// 5778.624 us; speedup vs baseline: 9.3567x; 1.1165x over previous
//
#include <hip/hip_runtime.h>
#include <hip/hip_bf16.h>

#define AS1 __attribute__((address_space(1)))
#define AS3 __attribute__((address_space(3)))

typedef unsigned short u16;
typedef __attribute__((ext_vector_type(8))) short short8;
typedef __attribute__((ext_vector_type(4))) float f32x4;

__device__ __forceinline__ float b2f(u16 u){ return __uint_as_float(((unsigned)u)<<16); }
__device__ __forceinline__ u16 f2b(float f){
  unsigned x = __float_as_uint(f);
  return (u16)((x + 0x7FFFu + ((x>>16)&1u)) >> 16);
}

// ---------- f32 -> bf16 cast ----------
__global__ __launch_bounds__(256)
void castk(const float* __restrict__ src, u16* __restrict__ dst, int n)
{
  const int i = (blockIdx.x*256 + threadIdx.x)*4;
  if (i < n){
    const f32x4 v = *(const f32x4*)(src + i);
    ushort4 o; o.x=f2b(v[0]); o.y=f2b(v[1]); o.z=f2b(v[2]); o.w=f2b(v[3]);
    *(ushort4*)(dst + i) = o;
  }
}

// ---------- MFMA GEMM with T2 XOR-swizzled LDS (pre-swizzled global src, swizzled ds_read) ----------
// LDS[r][g] = G[r][g ^ (r&7)] (16B granules); read granule = gi ^ (r&7). 2-way max aliasing = free.
// MODE 0: bf16 out; 1: bf16 relu; 2: f32 residual atomicAdd (ld 1024, opt remap; split-K via gridDim.z);
// MODE 3: f32 sigmoid; 4: f32 out
template<int MODE>
__global__ __launch_bounds__(256)
void gemm_bt(const u16* __restrict__ A, const u16* __restrict__ W,
             const float* __restrict__ bias, void* __restrict__ Cout,
             int N, int K, int remap)
{
  __shared__ u16 Al[128*64];
  __shared__ u16 Bl[128*64];
  const int tid  = threadIdx.x;
  const int lane = tid & 63;
  const int w    = tid >> 6;
  const int wr = (w>>1)*64, wc = (w&1)*64;
  const int fr = lane & 15;
  const int fk = (lane>>4)*8;
  const int r8 = tid >> 3;
  const int g  = tid & 7;
  const int gsw = (g ^ (r8 & 7)) * 8;     // swizzled source granule (u16 units); rows step by 32 so r&7 const
  const u16* ag = A + (size_t)(blockIdx.y*128 + r8)*K + gsw;
  const u16* bg = W + (size_t)(blockIdx.x*128 + r8)*K + gsw;
  u16* al = &Al[r8*64 + g*8];             // linear LDS dest (required by global_load_lds)
  u16* bl = &Bl[r8*64 + g*8];

  const int Klen = K / gridDim.z;
  const int kb   = Klen * blockIdx.z;

  f32x4 acc[4][4];
  #pragma unroll
  for (int m=0;m<4;++m)
    #pragma unroll
    for (int n=0;n<4;++n) acc[m][n] = (f32x4){0.f,0.f,0.f,0.f};

  const int frs = fr & 7;
  for (int kt=kb; kt<kb+Klen; kt+=64){
    #pragma unroll
    for (int r=0;r<4;++r){
      __builtin_amdgcn_global_load_lds((const AS1 void*)(ag + (size_t)(r*32)*K + kt),
                                       (AS3 void*)(al + r*32*64), 16, 0, 0);
      __builtin_amdgcn_global_load_lds((const AS1 void*)(bg + (size_t)(r*32)*K + kt),
                                       (AS3 void*)(bl + r*32*64), 16, 0, 0);
    }
    __syncthreads();
    #pragma unroll
    for (int kk=0; kk<64; kk+=32){
      const int gi = (kk + fk) >> 3;
      const int go = ((gi ^ frs) << 3);   // swizzled read granule offset (u16)
      short8 a[4], b[4];
      #pragma unroll
      for (int m=0;m<4;++m) a[m] = *(const short8*)&Al[(wr+m*16+fr)*64 + go];
      #pragma unroll
      for (int n=0;n<4;++n) b[n] = *(const short8*)&Bl[(wc+n*16+fr)*64 + go];
      #pragma unroll
      for (int m=0;m<4;++m)
        #pragma unroll
        for (int n=0;n<4;++n)
          acc[m][n] = __builtin_amdgcn_mfma_f32_16x16x32_bf16(a[m], b[n], acc[m][n], 0, 0, 0);
    }
    __syncthreads();
  }

  const int rsub = (lane>>4)*4;
  #pragma unroll
  for (int n=0;n<4;++n){
    const int col = blockIdx.x*128 + wc + n*16 + fr;
    const float bv = (MODE==2 && blockIdx.z != 0) ? 0.f : bias[col];
    #pragma unroll
    for (int m=0;m<4;++m){
      const int row0 = blockIdx.y*128 + wr + m*16 + rsub;
      #pragma unroll
      for (int r=0;r<4;++r){
        const int row = row0 + r;
        float v = acc[m][n][r] + bv;
        if (MODE==0) ((u16*)Cout)[(size_t)row*N + col] = f2b(v);
        else if (MODE==1) ((u16*)Cout)[(size_t)row*N + col] = f2b(fmaxf(v,0.f));
        else if (MODE==2){
          const int orow = remap ? ((row>>7)*144 + 16 + (row&127)) : row;
          atomicAdd((float*)Cout + (size_t)orow*1024 + col, v);
        }
        else if (MODE==3) ((float*)Cout)[(size_t)row*N + col] = 1.f/(1.f+expf(-v));
        else ((float*)Cout)[(size_t)row*N + col] = v;
      }
    }
  }
}

// ---------- MFMA attention: per-(b,h) block; KV rows j<16 from "mem" src, j>=16 from "enc" src ----------
__global__ __launch_bounds__(256)
void attn_kernel(const u16* __restrict__ Qp, int ldq,
                 const u16* __restrict__ Km, const u16* __restrict__ Vm, int ldm, size_t bsm,
                 const u16* __restrict__ Ke, const u16* __restrict__ Ve, int lde, size_t bse,
                 u16* __restrict__ Op, int nq, int qoff)
{
  __shared__ u16 Kl[144*64];
  __shared__ u16 Vt[64*160];
  __shared__ u16 Pl[4][16*160];
  const int tid = threadIdx.x, lane = tid & 63, w = tid >> 6;
  const int b = blockIdx.x >> 4, h = blockIdx.x & 15;
  const u16* Qb = Qp + (size_t)(b*nq)*ldq + h*64;
  u16* Ob = Op + (size_t)(b*nq)*1024 + h*64;

  for (int i = tid*4; i < 64*160; i += 1024){ ushort4 zz = {0,0,0,0}; *(ushort4*)&Vt[i] = zz; }
  for (int i = tid*4; i < 4*16*160; i += 1024){ ushort4 zz = {0,0,0,0}; *(ushort4*)&Pl[0][i] = zz; }
  __syncthreads();

  for (int idx = tid*4; idx < 144*64; idx += 1024){
    const int j = idx >> 6, c = idx & 63;
    const u16* Kr = (j < 16) ? (Km + (size_t)b*bsm + (size_t)j*ldm + h*64)
                             : (Ke + (size_t)b*bse + (size_t)(j-16)*lde + h*64);
    const u16* Vr = (j < 16) ? (Vm + (size_t)b*bsm + (size_t)j*ldm + h*64)
                             : (Ve + (size_t)b*bse + (size_t)(j-16)*lde + h*64);
    ushort4 kk4 = *(const ushort4*)(Kr + c);
    *(ushort4*)&Kl[j*64 + c] = kk4;
    ushort4 vv4 = *(const ushort4*)(Vr + c);
    Vt[(c+0)*160 + j] = vv4.x; Vt[(c+1)*160 + j] = vv4.y;
    Vt[(c+2)*160 + j] = vv4.z; Vt[(c+3)*160 + j] = vv4.w;
  }
  __syncthreads();

  const int fr = lane & 15;
  const int fkb = (lane>>4)*8;
  const int rsub = (lane>>4)*4;
  const int ntiles = nq >> 4;
  for (int qt = w; qt < ntiles; qt += 4){
    const int t0 = qt*16;
    short8 qa0 = *(const short8*)(Qb + (size_t)(t0+fr)*ldq + fkb);
    short8 qa1 = *(const short8*)(Qb + (size_t)(t0+fr)*ldq + 32 + fkb);
    f32x4 s[9];
    #pragma unroll
    for (int ct=0; ct<9; ++ct){
      f32x4 z = (f32x4){0.f,0.f,0.f,0.f};
      short8 b0 = *(const short8*)&Kl[(ct*16+fr)*64 + fkb];
      z = __builtin_amdgcn_mfma_f32_16x16x32_bf16(qa0, b0, z, 0,0,0);
      short8 b1 = *(const short8*)&Kl[(ct*16+fr)*64 + 32 + fkb];
      z = __builtin_amdgcn_mfma_f32_16x16x32_bf16(qa1, b1, z, 0,0,0);
      s[ct] = z;
    }
    #pragma unroll
    for (int r=0;r<4;++r){
      const int t = t0 + rsub + r;
      const int qi = t + qoff;
      float vals[9];
      float mx = -1e30f;
      #pragma unroll
      for (int ct=0; ct<9; ++ct){
        const int j = ct*16 + fr;
        float v = s[ct][r] * 0.125f;
        if (qi >= 0 && j >= 16 && (j-16) > qi) v = -1e30f;
        vals[ct] = v; mx = fmaxf(mx, v);
      }
      #pragma unroll
      for (int d=1; d<16; d<<=1) mx = fmaxf(mx, __shfl_xor(mx, d));
      float sum = 0.f;
      #pragma unroll
      for (int ct=0; ct<9; ++ct){ float e = expf(vals[ct]-mx); vals[ct] = e; sum += e; }
      #pragma unroll
      for (int d=1; d<16; d<<=1) sum += __shfl_xor(sum, d);
      const float inv = 1.f/sum;
      #pragma unroll
      for (int ct=0; ct<9; ++ct) Pl[w][(rsub+r)*160 + ct*16 + fr] = f2b(vals[ct]*inv);
    }
    #pragma unroll
    for (int oc=0; oc<4; ++oc){
      f32x4 o = (f32x4){0.f,0.f,0.f,0.f};
      #pragma unroll
      for (int ks=0; ks<5; ++ks){
        short8 pa = *(const short8*)&Pl[w][fr*160 + ks*32 + fkb];
        short8 vb = *(const short8*)&Vt[(oc*16+fr)*160 + ks*32 + fkb];
        o = __builtin_amdgcn_mfma_f32_16x16x32_bf16(pa, vb, o, 0,0,0);
      }
      #pragma unroll
      for (int r=0;r<4;++r)
        Ob[(size_t)(t0+rsub+r)*1024 + oc*16 + fr] = f2b(o[r]);
    }
  }
}

// ---------- LN helpers ----------
__device__ __forceinline__ void ln_stats(float s, float s2, float* red, int tid,
                                         float& mu, float& rstd)
{
  #pragma unroll
  for (int d=1; d<64; d<<=1){ s += __shfl_xor(s,d); s2 += __shfl_xor(s2,d); }
  if ((tid&63)==0){ red[tid>>6] = s; red[4+(tid>>6)] = s2; }
  __syncthreads();
  s  = red[0]+red[1]+red[2]+red[3];
  s2 = red[4]+red[5]+red[6]+red[7];
  mu = s * (1.f/1024.f);
  float var = s2*(1.f/1024.f) - mu*mu;
  rstd = rsqrtf(fmaxf(var,0.f) + 1e-5f);
}

__global__ __launch_bounds__(256)
void buildz_ln(const float* __restrict__ mem, const int* __restrict__ ids,
               const float* __restrict__ emb, const float* __restrict__ pos,
               const float* __restrict__ gam, const float* __restrict__ bet,
               float* __restrict__ z, u16* __restrict__ out, int k)
{
  __shared__ float red[8];
  const int row = blockIdx.x;
  const int b = row / 144, t = row % 144;
  const int tid = threadIdx.x, c0 = tid*4;
  float v[4];
  if (t < 16){
    const f32x4 mv = *(const f32x4*)(mem + (size_t)(b*16+t)*1024 + c0);
    v[0]=mv[0]; v[1]=mv[1]; v[2]=mv[2]; v[3]=mv[3];
  } else {
    const int tok = ids[b*2048 + k*128 + (t-16)];
    const f32x4 e4 = *(const f32x4*)(emb + (size_t)tok*1024 + c0);
    v[0]=e4[0]; v[1]=e4[1]; v[2]=e4[2]; v[3]=e4[3];
  }
  const f32x4 p4 = *(const f32x4*)(pos + (size_t)t*1024 + c0);
  v[0]+=p4[0]; v[1]+=p4[1]; v[2]+=p4[2]; v[3]+=p4[3];
  f32x4 zz; zz[0]=v[0]; zz[1]=v[1]; zz[2]=v[2]; zz[3]=v[3];
  *(f32x4*)(z + (size_t)row*1024 + c0) = zz;
  float s = v[0]+v[1]+v[2]+v[3];
  float s2 = v[0]*v[0]+v[1]*v[1]+v[2]*v[2]+v[3]*v[3];
  float mu, rstd; ln_stats(s, s2, red, tid, mu, rstd);
  const f32x4 g4 = *(const f32x4*)(gam + c0);
  const f32x4 b4 = *(const f32x4*)(bet + c0);
  ushort4 o4;
  o4.x = f2b((v[0]-mu)*rstd*g4[0]+b4[0]);
  o4.y = f2b((v[1]-mu)*rstd*g4[1]+b4[1]);
  o4.z = f2b((v[2]-mu)*rstd*g4[2]+b4[2]);
  o4.w = f2b((v[3]-mu)*rstd*g4[3]+b4[3]);
  *(ushort4*)(out + (size_t)row*1024 + c0) = o4;
}

__global__ __launch_bounds__(256)
void ln_f32(const float* __restrict__ src, const float* __restrict__ gam,
            const float* __restrict__ bet, u16* __restrict__ out, int remap)
{
  __shared__ float red[8];
  const int row = blockIdx.x;
  const int srow = remap ? ((row>>7)*144 + 16 + (row&127)) : row;
  const int tid = threadIdx.x, c0 = tid*4;
  const f32x4 xv = *(const f32x4*)(src + (size_t)srow*1024 + c0);
  float v[4] = {xv[0], xv[1], xv[2], xv[3]};
  float s = v[0]+v[1]+v[2]+v[3];
  float s2 = v[0]*v[0]+v[1]*v[1]+v[2]*v[2]+v[3]*v[3];
  float mu, rstd; ln_stats(s, s2, red, tid, mu, rstd);
  const f32x4 g4 = *(const f32x4*)(gam + c0);
  const f32x4 b4 = *(const f32x4*)(bet + c0);
  ushort4 o4;
  o4.x = f2b((v[0]-mu)*rstd*g4[0]+b4[0]);
  o4.y = f2b((v[1]-mu)*rstd*g4[1]+b4[1]);
  o4.z = f2b((v[2]-mu)*rstd*g4[2]+b4[2]);
  o4.w = f2b((v[3]-mu)*rstd*g4[3]+b4[3]);
  *(ushort4*)(out + (size_t)row*1024 + c0) = o4;
}

// LN over bf16 source rows (for proj_mem)
__global__ __launch_bounds__(256)
void ln_b16(const u16* __restrict__ src, const float* __restrict__ gam,
            const float* __restrict__ bet, u16* __restrict__ out)
{
  __shared__ float red[8];
  const int row = blockIdx.x;
  const int tid = threadIdx.x, c0 = tid*4;
  const ushort4 x4 = *(const ushort4*)(src + (size_t)row*1024 + c0);
  float v[4] = {b2f(x4.x), b2f(x4.y), b2f(x4.z), b2f(x4.w)};
  float s = v[0]+v[1]+v[2]+v[3];
  float s2 = v[0]*v[0]+v[1]*v[1]+v[2]*v[2]+v[3]*v[3];
  float mu, rstd; ln_stats(s, s2, red, tid, mu, rstd);
  const f32x4 g4 = *(const f32x4*)(gam + c0);
  const f32x4 b4 = *(const f32x4*)(bet + c0);
  ushort4 o4;
  o4.x = f2b((v[0]-mu)*rstd*g4[0]+b4[0]);
  o4.y = f2b((v[1]-mu)*rstd*g4[1]+b4[1]);
  o4.z = f2b((v[2]-mu)*rstd*g4[2]+b4[2]);
  o4.w = f2b((v[3]-mu)*rstd*g4[3]+b4[3]);
  *(ushort4*)(out + (size_t)row*1024 + c0) = o4;
}

__global__ __launch_bounds__(256)
void mc_cast(const float* __restrict__ z, u16* __restrict__ mcb)
{
  const int i = blockIdx.x*1024 + threadIdx.x*4;
  const int r = i >> 10, c = i & 1023;
  const int b = r >> 4, t = r & 15;
  const f32x4 zv = *(const f32x4*)(z + (size_t)(b*144+t)*1024 + c);
  ushort4 o4; o4.x=f2b(zv[0]); o4.y=f2b(zv[1]); o4.z=f2b(zv[2]); o4.w=f2b(zv[3]);
  *(ushort4*)(mcb + i) = o4;
}

__global__ __launch_bounds__(256)
void gate_apply(const float* __restrict__ z, const float* __restrict__ gate,
                float* __restrict__ mem, int k)
{
  const int i = blockIdx.x*1024 + threadIdx.x*4;
  const int r = i >> 10, c = i & 1023;
  const int b = r >> 4, t = r & 15;
  const f32x4 mc = *(const f32x4*)(z + (size_t)(b*144+t)*1024 + c);
  f32x4 out;
  if (k == 0){
    out = mc;
  } else {
    const f32x4 gg = *(const f32x4*)(gate + i);
    const f32x4 mo = *(const f32x4*)(mem + i);
    out[0] = gg[0]*mc[0] + (1.f-gg[0])*mo[0];
    out[1] = gg[1]*mc[1] + (1.f-gg[1])*mo[1];
    out[2] = gg[2]*mc[2] + (1.f-gg[2])*mo[2];
    out[3] = gg[3]*mc[3] + (1.f-gg[3])*mo[3];
  }
  *(f32x4*)(mem + i) = out;
}

__global__ __launch_bounds__(256)
void writeout(const float* __restrict__ z, float* __restrict__ out, int k)
{
  const int row = blockIdx.x;
  const int b = row >> 7, t = row & 127;
  const int c0 = threadIdx.x*4;
  const f32x4 zv = *(const f32x4*)(z + (size_t)(b*144+16+t)*1024 + c0);
  *(f32x4*)(out + ((size_t)b*2048 + k*128 + t)*1024 + c0) = zv;
}

extern "C" void kernel_launch(void* const* d_in, const int* in_sizes, int n_in,
                              void* d_out, int out_size, void* d_ws, size_t ws_size,
                              hipStream_t stream)
{
  const int*   in_res   = (const int*)d_in[0];
  const float* enc_out  = (const float*)d_in[1];
  const float* enc_mem  = (const float*)d_in[2];
  const float* emb      = (const float*)d_in[3];
  const float* Wmem     = (const float*)d_in[4];
  const float* bmem     = (const float*)d_in[5];
  const float* pos      = (const float*)d_in[6];
  const float* Wqkv_s   = (const float*)d_in[7];
  const float* bqkv_s   = (const float*)d_in[8];
  const float* Wo_s     = (const float*)d_in[9];
  const float* bo_s     = (const float*)d_in[10];
  const float* g_la     = (const float*)d_in[11];
  const float* b_la     = (const float*)d_in[12];
  const float* W1       = (const float*)d_in[13];
  const float* b1       = (const float*)d_in[14];
  const float* W2       = (const float*)d_in[15];
  const float* b2       = (const float*)d_in[16];
  const float* g_lf     = (const float*)d_in[17];
  const float* b_lf     = (const float*)d_in[18];
  const float* Wencm    = (const float*)d_in[19];
  const float* bencm    = (const float*)d_in[20];
  const float* Wqkv_c   = (const float*)d_in[21];
  const float* bqkv_c   = (const float*)d_in[22];
  const float* Wo_c     = (const float*)d_in[23];
  const float* bo_c     = (const float*)d_in[24];
  const float* g_lq     = (const float*)d_in[25];
  const float* b_lq     = (const float*)d_in[26];
  const float* g_lkv    = (const float*)d_in[27];
  const float* b_lkv    = (const float*)d_in[28];
  const float* W1c      = (const float*)d_in[29];
  const float* b1c      = (const float*)d_in[30];
  const float* W2c      = (const float*)d_in[31];
  const float* b2c      = (const float*)d_in[32];
  const float* g_lfc    = (const float*)d_in[33];
  const float* b_lfc    = (const float*)d_in[34];
  const float* Wg       = (const float*)d_in[35];
  const float* bg       = (const float*)d_in[36];

  char* ws = (char*)d_ws;
  size_t off = 0;
  auto alloc = [&](size_t bytes)->void*{
    void* p = ws + off; off += (bytes + 255) & ~(size_t)255; return p;
  };
  float* z     = (float*)alloc((size_t)2304*1024*4);
  u16*  lnbuf  = (u16*) alloc((size_t)2304*1024*2);
  u16*  qkv    = (u16*) alloc((size_t)2304*3072*2);
  u16*  attnb  = (u16*) alloc((size_t)2304*1024*2);
  u16*  mid    = (u16*) alloc((size_t)2304*4096*2);
  float* memf  = (float*)alloc((size_t)256*1024*4);
  u16*  pmem   = (u16*) alloc((size_t)256*1024*2);
  u16*  mcb    = (u16*) alloc((size_t)256*1024*2);
  float* gate  = (float*)alloc((size_t)256*1024*4);
  u16*  kvmln  = (u16*) alloc((size_t)256*1024*2);
  u16*  kvmem  = (u16*) alloc((size_t)256*2048*2);
  u16*  kveln  = (u16*) alloc((size_t)32768*1024*2);
  const int DD = 1024*1024, D3 = 3*1024*1024, DFD = 4096*1024;
  u16* wWmem   = (u16*)alloc((size_t)DD*2);
  u16* wWqkv_s = (u16*)alloc((size_t)D3*2);
  u16* wWo_s   = (u16*)alloc((size_t)DD*2);
  u16* wW1     = (u16*)alloc((size_t)DFD*2);
  u16* wW2     = (u16*)alloc((size_t)DFD*2);
  u16* wWencm  = (u16*)alloc((size_t)DD*2);
  u16* wWqkv_c = (u16*)alloc((size_t)D3*2);
  u16* wWo_c   = (u16*)alloc((size_t)DD*2);
  u16* wW1c    = (u16*)alloc((size_t)DFD*2);
  u16* wW2c    = (u16*)alloc((size_t)DFD*2);
  u16* wWg     = (u16*)alloc((size_t)DD*2);
  u16* encmb   = (u16*)alloc((size_t)256*1024*2);

  u16* qc  = qkv;
  float* outf = (float*)d_out;
  u16*  kvenc = (u16*)d_out;

  dim3 blk(256);
  castk<<<DD/1024,  blk, 0, stream>>>(Wmem,   wWmem,   DD);
  castk<<<D3/1024,  blk, 0, stream>>>(Wqkv_s, wWqkv_s, D3);
  castk<<<DD/1024,  blk, 0, stream>>>(Wo_s,   wWo_s,   DD);
  castk<<<DFD/1024, blk, 0, stream>>>(W1,     wW1,     DFD);
  castk<<<DFD/1024, blk, 0, stream>>>(W2,     wW2,     DFD);
  castk<<<DD/1024,  blk, 0, stream>>>(Wencm,  wWencm,  DD);
  castk<<<D3/1024,  blk, 0, stream>>>(Wqkv_c, wWqkv_c, D3);
  castk<<<DD/1024,  blk, 0, stream>>>(Wo_c,   wWo_c,   DD);
  castk<<<DFD/1024, blk, 0, stream>>>(W1c,    wW1c,    DFD);
  castk<<<DFD/1024, blk, 0, stream>>>(W2c,    wW2c,    DFD);
  castk<<<DD/1024,  blk, 0, stream>>>(Wg,     wWg,     DD);
  castk<<<256,      blk, 0, stream>>>(enc_mem, encmb,  256*1024);

  gemm_bt<4><<<dim3(8,2), blk, 0, stream>>>(encmb, wWmem,  bmem,  memf, 1024, 1024, 0);
  gemm_bt<0><<<dim3(8,2), blk, 0, stream>>>(encmb, wWencm, bencm, pmem, 1024, 1024, 0);

  ln_f32<<<32768, blk, 0, stream>>>(enc_out, g_lkv, b_lkv, kveln, 0);
  ln_b16<<<256,   blk, 0, stream>>>(pmem, g_lkv, b_lkv, kvmln);
  gemm_bt<0><<<dim3(16,256), blk, 0, stream>>>(kveln, wWqkv_c + (size_t)1024*1024,
                                               bqkv_c + 1024, kvenc, 2048, 1024, 0);
  gemm_bt<0><<<dim3(16,2),   blk, 0, stream>>>(kvmln, wWqkv_c + (size_t)1024*1024,
                                               bqkv_c + 1024, kvmem, 2048, 1024, 0);

  const size_t bsm_c = (size_t)16*2048;
  const size_t bse_c = (size_t)2048*2048;
  const size_t bss   = (size_t)144*3072;

  for (int k = 0; k < 16; ++k){
    buildz_ln<<<2304, blk, 0, stream>>>(memf, in_res, emb, pos, g_la, b_la, z, lnbuf, k);
    gemm_bt<0><<<dim3(24,18), blk, 0, stream>>>(lnbuf, wWqkv_s, bqkv_s, qkv, 3072, 1024, 0);
    attn_kernel<<<256, blk, 0, stream>>>(qkv, 3072,
                                         qkv+1024, qkv+2048, 3072, bss,
                                         qkv+1024+(size_t)16*3072, qkv+2048+(size_t)16*3072, 3072, bss,
                                         attnb, 144, -16);
    gemm_bt<2><<<dim3(8,18,2), blk, 0, stream>>>(attnb, wWo_s, bo_s, z, 1024, 1024, 0);
    ln_f32<<<2304, blk, 0, stream>>>(z, g_lf, b_lf, lnbuf, 0);
    gemm_bt<1><<<dim3(32,18), blk, 0, stream>>>(lnbuf, wW1, b1, mid, 4096, 1024, 0);
    gemm_bt<2><<<dim3(8,18,4), blk, 0, stream>>>(mid, wW2, b2, z, 1024, 4096, 0);
    // cross block
    ln_f32<<<2048, blk, 0, stream>>>(z, g_lq, b_lq, lnbuf, 1);
    gemm_bt<0><<<dim3(8,16), blk, 0, stream>>>(lnbuf, wWqkv_c, bqkv_c, qc, 1024, 1024, 0);
    attn_kernel<<<256, blk, 0, stream>>>(qc, 1024,
                                         kvmem, kvmem+1024, 2048, bsm_c,
                                         kvenc + (size_t)k*128*2048, kvenc + (size_t)k*128*2048 + 1024, 2048, bse_c,
                                         attnb, 128, 0);
    gemm_bt<2><<<dim3(8,16,2), blk, 0, stream>>>(attnb, wWo_c, bo_c, z, 1024, 1024, 1);
    ln_f32<<<2048, blk, 0, stream>>>(z, g_lfc, b_lfc, lnbuf, 1);
    gemm_bt<1><<<dim3(32,16), blk, 0, stream>>>(lnbuf, wW1c, b1c, mid, 4096, 1024, 0);
    gemm_bt<2><<<dim3(8,16,4), blk, 0, stream>>>(mid, wW2c, b2c, z, 1024, 4096, 1);
    writeout<<<2048, blk, 0, stream>>>(z, outf, k);
    // memory gate
    mc_cast<<<256, blk, 0, stream>>>(z, mcb);
    gemm_bt<3><<<dim3(8,2), blk, 0, stream>>>(mcb, wWg, bg, gate, 1024, 1024, 0);
    gate_apply<<<256, blk, 0, stream>>>(z, gate, memf, k);
  }
}